// Round 9
// baseline (499.854 us; speedup 1.0000x reference)
//
#include <hip/hip_runtime.h>
#include <math.h>

// SwarmSetEquivariantTorso — bf16 MFMA, N-split block GEMMs, 12 tok/block.
// HISTORY: R0 375us | R5 act-reuse 463us (FAIL: weight-batch vmcnt stalls)
// R7 8tok/4blk-CU 437us (FAIL: occupancy up, per-block fixed cost up)
// R8 361us (WIN: cross-barrier weight prefetch + non-draining BAR()).
// THIS VERSION = R8 + ONE change: o-proj switched N-split -> M-split
// (wave wv owns M-tile wv, all 4 N-tiles => full rows in registers), so
// residual + ln2 fuse into its epilogue (shfl_xor 16/32 row stats, same
// as ln1). Eliminates the ln2 phase: 18 -> 17 barriers, drops ln2's
// LDS round-trip + glue VALU. W_A1O loaded 4x redundantly (L2-hot, idle
// pipe). Tk rows 60-63 zero-init'd (fused phase reads all 16 rows/tile).

#define DOBS 198
#define NEG_INF_F (-3.402823466e38f)

// Non-draining barrier: LDS visibility via lgkmcnt(0); global (weight)
// loads stay in flight. No cross-wave global communication in-kernel.
#define BAR() do { asm volatile("s_waitcnt lgkmcnt(0)" ::: "memory"); \
                   __builtin_amdgcn_s_barrier(); } while(0)

typedef __bf16 v8bf __attribute__((ext_vector_type(8)));
typedef __bf16 v4bf __attribute__((ext_vector_type(4)));
typedef float  v4f  __attribute__((ext_vector_type(4)));

struct P {
  const float *obs,*tok_w,*tok_b,*ln1_s,*ln1_b,
    *a1_qw,*a1_qb,*a1_kw,*a1_kb,*a1_vw,*a1_vb,*a1_ow,*a1_ob,
    *ln2_s,*ln2_b,*m1_w,*m1_b,*m2_w,*m2_b,*m3_w,*m3_b,
    *e1_w,*e1_b,*e2_w,*e2_b,*e3_w,*e3_b,
    *l1_w,*l1_b,*l2_w,*l2_b,*l3_w,*l3_b,
    *seed,*p_qw,*p_qb,*p_kw,*p_kb,*p_vw,*p_vb,*p_ow,*p_ob,
    *pr_w,*pr_b,*h1_w,*h1_b,*h2_w,*h2_b,*h3_w,*h3_b;
  float* out;
};
static_assert(sizeof(P) == 51*sizeof(void*), "P layout");

// ws bf16 weight image, W_t[n][k] per matrix (element offsets)
#define W_A1Q 0
#define W_A1K 4096
#define W_A1V 8192
#define W_A1O 12288
#define W_M1  16384
#define W_M2  24576
#define W_M3  40960
#define W_E1  49152
#define W_E2  53248
#define W_E3  69632
#define W_L1  77824
#define W_L2  94208
#define W_PK  110592
#define W_PV  114688
#define W_PO  118784
#define W_H1  122880
#define W_H2  143360
#define W_H3  159744
#define W_END 176128
#define W_QP  176128   // + 64 f32 (pooling query, precomputed)

__global__ __launch_bounds__(256)
void prep_w(P a, __bf16* ws)
{
  if (blockIdx.x == 172){
    int t = threadIdx.x;
    if (t < 64){
      float acc = a.p_qb[t];
      for (int k=0;k<64;k++) acc += a.seed[k]*a.p_qw[k*64+t];
      ((float*)(ws + W_QP))[t] = acc;
    }
    return;
  }
  const float* srcs[18] = {a.a1_qw,a.a1_kw,a.a1_vw,a.a1_ow,a.m1_w,a.m2_w,a.m3_w,
                           a.e1_w,a.e2_w,a.e3_w,a.l1_w,a.l2_w,a.p_kw,a.p_vw,a.p_ow,
                           a.h1_w,a.h2_w,a.h3_w};
  const int Ks[18]   = {64,64,64,64,64,128,128,32,128,128,128,128,64,64,64,160,128,128};
  const int Ns[18]   = {64,64,64,64,128,128,64,128,128,64,128,128,64,64,64,128,128,128};
  const int offs[18] = {W_A1Q,W_A1K,W_A1V,W_A1O,W_M1,W_M2,W_M3,W_E1,W_E2,W_E3,
                        W_L1,W_L2,W_PK,W_PV,W_PO,W_H1,W_H2,W_H3};
  __shared__ float tile[32][33];
  int b = blockIdx.x, m = 0, acc = 0;
  for (; m < 18; m++){
    int t = (Ks[m]/32)*(Ns[m]/32);
    if (b < acc + t) break;
    acc += t;
  }
  int lt = b - acc, K = Ks[m], N = Ns[m];
  int ntile = N/32, kt = lt/ntile, nt = lt%ntile;
  int tx = threadIdx.x & 31, ty = threadIdx.x >> 5;
  const float* S = srcs[m];
  #pragma unroll
  for (int rr=0; rr<32; rr+=8)
    tile[ty+rr][tx] = S[(size_t)(kt*32+ty+rr)*N + nt*32+tx];
  __syncthreads();
  __bf16* D = ws + offs[m];
  #pragma unroll
  for (int rr=0; rr<32; rr+=8)
    D[(size_t)(nt*32+ty+rr)*K + kt*32+tx] = (__bf16)tile[tx][ty+rr];
}

// gelu(x) = x * sigmoid(2t),  t = 0.79788456(x + 0.044715 x^3)  (exact tanh form)
__device__ __forceinline__ float gelu_f(float x){
  float t = x * fmaf(0.0356774081f, x*x, 0.7978845608f);
  float u = __builtin_amdgcn_exp2f(-2.885390082f * t);
  return x * __builtin_amdgcn_rcpf(1.0f + u);
}

__device__ __forceinline__ void load16f(const __bf16* p, float* f){
  v8bf a = *(const v8bf*)p, b = *(const v8bf*)(p+8);
  #pragma unroll
  for (int i=0;i<8;i++){ f[i]=(float)a[i]; f[8+i]=(float)b[i]; }
}

// Weight fragments for one N-split gemm call: issued early (prefetch),
// consumed after the next barrier. All indices compile-time (stays in regs).
template<int KT,int NTPW> struct WF {
  v8bf  w[NTPW][KT];
  float4 b[NTPW];
};

template<int KT,int NTPW>
__device__ __forceinline__ WF<KT,NTPW> wload(const __bf16* __restrict__ Wt,
    const float* __restrict__ bias, int wv, int lane)
{
  WF<KT,NTPW> f;
  const int ar = lane&15, quad = lane>>4;
  #pragma unroll
  for (int ln=0; ln<NTPW; ln++){
    const int wt = wv*NTPW + ln;
    const __bf16* wp = Wt + (size_t)(wt*16+ar)*(KT*32) + quad*8;
    #pragma unroll
    for (int kt=0;kt<KT;kt++) f.w[ln][kt] = *(const v8bf*)(wp + kt*32);
    f.b[ln] = *(const float4*)(bias + wt*16 + quad*4);
  }
  return f;
}

// All-N-tiles loader (for M-split gemms: every wave needs every N-tile).
template<int KT,int NT>
__device__ __forceinline__ WF<KT,NT> wloadA(const __bf16* __restrict__ Wt,
    const float* __restrict__ bias, int lane)
{
  WF<KT,NT> f;
  const int ar = lane&15, quad = lane>>4;
  #pragma unroll
  for (int ln=0; ln<NT; ln++){
    const __bf16* wp = Wt + (size_t)(ln*16+ar)*(KT*32) + quad*8;
    #pragma unroll
    for (int kt=0;kt<KT;kt++) f.w[ln][kt] = *(const v8bf*)(wp + kt*32);
    f.b[ln] = *(const float4*)(bias + ln*16 + quad*4);
  }
  return f;
}

// N-split block GEMM consuming prefetched weights: D[60+pad x N] = act@W+b.
// Wave wv owns N-tiles wv*NTPW..; loops MT M-tiles; act frags from LDS.
template<int KT,int MT,int NTPW,typename LA,typename E>
__device__ __forceinline__ void gemmW(LA la, const WF<KT,NTPW>& f,
    int wv, int lane, E epi)
{
  const int ar = lane&15, quad = lane>>4;
  #pragma unroll
  for (int ln=0; ln<NTPW; ln++){
    const int wt = wv*NTPW + ln;
    #pragma unroll
    for (int mt=0; mt<MT; mt++){
      v4f c; c[0]=f.b[ln].x; c[1]=f.b[ln].y; c[2]=f.b[ln].z; c[3]=f.b[ln].w;
      #pragma unroll
      for (int kt=0;kt<KT;kt++)
        c = __builtin_amdgcn_mfma_f32_16x16x32_bf16(f.w[ln][kt], la(mt,kt,ar,quad), c, 0,0,0);
      epi(wt*16 + quad*4, mt, ar, c);
    }
  }
}

// LDS map (bytes), total 53120 <= 53248 (proven 3 blocks/CU):
//  Ab   @0      bf16[64][136] 17408  (early: Df f32[12][32])
//  Bb   @17408  bf16[64][136] 17408  (early: TOKIN f32[60][12])
//  Tk   @34816  bf16[64][72]   9216  (early: OBSf f32[12][120]; late: Po bf16[12][64])
//  Pe   @44032  bf16[16][64]   2048
//  Eg   @46080  bf16[16][40]   1280
//  Ru   @47360  bf16[12][30]    736
//  mfb  @48096  bf16[64]        128
//  msfb @48224  bf16[64]        128
//  many @48352  f32[16]          64
//  lga  @48416  f32[64]         256
//  ECX  @48672  bf16[16][64]   2048  (late: pattn f32[12][20])
//  ATTb @50720  bf16[12][100]  2400  (late: Cc bf16[16][64])
__global__ __launch_bounds__(256,3)
void swarm_mfma(P a, const __bf16* __restrict__ ws, int ntok)
{
  __shared__ char smem[53120] __attribute__((aligned(16)));
  __bf16* Ab   = (__bf16*)(smem);
  __bf16* Bb   = (__bf16*)(smem+17408);
  float*  TOKIN= (float*) (smem+17408);
  __bf16* Tk   = (__bf16*)(smem+34816);
  float*  OBSf = (float*) (smem+34816);
  __bf16* Po   = (__bf16*)(smem+34816);
  __bf16* Pe   = (__bf16*)(smem+44032);
  __bf16* Eg   = (__bf16*)(smem+46080);
  __bf16* Ru   = (__bf16*)(smem+47360);
  __bf16* mfb  = (__bf16*)(smem+48096);
  __bf16* msfb = (__bf16*)(smem+48224);
  float*  many = (float*) (smem+48352);
  float*  lga  = (float*) (smem+48416);
  __bf16* ECX  = (__bf16*)(smem+48672);
  float*  pattn= (float*) (smem+48672);
  __bf16* ATTb = (__bf16*)(smem+50720);
  __bf16* Cc   = (__bf16*)(smem+50720);

  const int lane = threadIdx.x & 63;
  const int wv   = threadIdx.x >> 6;
  const int ar   = lane & 15, quad = lane >> 4;
  const long blkT0 = (long)blockIdx.x*12;

  // ================= setup (wave-local tokens 3wv..3wv+2) =================
  for (int it=lane; it<3*117; it+=64){
    int tg=it/117, c=it-tg*117;
    long gt = blkT0 + 3*wv + tg; if (gt>ntok-1) gt=ntok-1;
    OBSf[(3*wv+tg)*120+c] = a.obs[gt*DOBS+c];
  }
  float* Df = (float*)Ab;
  for (int it=lane; it<75; it+=64){
    int tg=it/25, p=it-tg*25, i=p/5, j=p-i*5;
    const float* ob = OBSf + (3*wv+tg)*120 + 32;
    float d2=0.f;
    #pragma unroll
    for (int d=0;d<3;d++){
      float ri=ob[15*i+d]; ri = isfinite(ri)?ri:0.f;
      float rj=ob[15*j+d]; rj = isfinite(rj)?rj:0.f;
      float df=ri-rj; d2 += df*df;
    }
    Df[(3*wv+tg)*32+p]=sqrtf(d2);
  }
  if (wv==1){  // zero Tk pad rows 60..63 (fused o-proj+ln2 reads all 16 rows/tile)
    for (int it=lane; it<288; it+=64) Tk[60*72+it] = (__bf16)0.f;
  }
  if (lane<15){
    int T=3*wv+lane/5, s=lane%5;
    const float* b = OBSf + T*120 + 32 + 15*s;
    mfb[15*wv+lane] = (__bf16)((fabsf(b[0])>1e-6f||fabsf(b[1])>1e-6f||fabsf(b[2])>1e-6f)?1.f:0.f);
  }
  if (wv==0 && lane>=60){ mfb[lane]=(__bf16)0.f; msfb[lane]=(__bf16)0.f; }
  if (wv==0 && lane>=12 && lane<16) many[lane]=0.f;
  if (lane<3){
    int T=3*wv+lane;
    float any = (float)mfb[T*5]+(float)mfb[T*5+1]+(float)mfb[T*5+2]+(float)mfb[T*5+3]+(float)mfb[T*5+4];
    float anyf = (any>0.f)?1.f:0.f; many[T]=anyf;
    #pragma unroll
    for (int i=0;i<5;i++) msfb[T*5+i] = (anyf>0.f)? mfb[T*5+i] : (__bf16)((i==0)?1.f:0.f);
  }
  if (lane<15){
    int T=3*wv+lane/5, i=lane%5, R=15*wv+lane;
    float dmin=1e9f,dsum=0.f,cnt=0.f;
    #pragma unroll
    for (int j=0;j<5;j++){
      if (j!=i && (float)mfb[T*5+i]>0.5f && (float)mfb[T*5+j]>0.5f){
        float dd=Df[T*32+i*5+j];
        dmin=fminf(dmin,dd); dsum+=dd; cnt+=1.f;
      }
    }
    TOKIN[R*12+10]=dmin;
    TOKIN[R*12+11]=(cnt>0.f)? dsum/(cnt+1e-9f) : 0.f;
  }
  for (int it=lane; it<150; it+=64){
    int tg=it/50, q=it-tg*50, s=q/10, c=q-s*10;
    int T=3*wv+tg;
    const float* b = OBSf + T*120 + 32 + 15*s;
    float v;
    if (c<4)        v=b[11+c];
    else if (c==4)  v=b[9];
    else if (c==5)  v=b[10];
    else if (c<9)   v=b[6+(c-6)];
    else { float a0=b[6],a1=b[7],a2=b[8]; v=sqrtf(a0*a0+a1*a1+a2*a2); }
    TOKIN[(T*5+s)*12+c]=v;
  }
  for (int it=lane; it<96; it+=64){
    int tg=it>>5, c=it&31;
    Eg[(3*wv+tg)*40+c] = (__bf16)OBSf[(3*wv+tg)*120+c];
  }
  for (int it=lane; it<90; it+=64){
    int tg=it/30, c=it-tg*30;
    Ru[(3*wv+tg)*30+c] = (__bf16)OBSf[(3*wv+tg)*120+32+15*(c/6)+(c%6)];
  }
  for (int it=lane; it<192; it+=64){
    int tg=it>>6, c=it&63;
    float acc = a.pr_b[c];
    #pragma unroll
    for (int k=0;k<10;k++) acc += OBSf[(3*wv+tg)*120+107+k]*a.pr_w[k*64+c];
    Pe[(3*wv+tg)*64+c] = (__bf16)gelu_f(acc);
  }
  BAR();   // S0: OBSf/Df/TOKIN producers done; Tk writes may begin

  // prefetch first gemm's weights; overlaps tok-embed + ln1
  auto wfK = wload<2,1>(ws+W_A1K, a.a1_kb, wv, lane);

  // ---- P3: tok embed (fp32 K=12) -> Tk rows 15wv..15wv+14; then ln1 -> Ab ----
  {
    float w0[12];
    #pragma unroll
    for (int k=0;k<12;k++) w0[k] = a.tok_w[k*64+lane];
    float tb = a.tok_b[lane];
    for (int r=0;r<15;r++){
      int R = 15*wv + r;
      const float4* tin = (const float4*)(TOKIN + R*12);
      float4 x0 = tin[0], x1 = tin[1], x2 = tin[2];
      float acc = tb;
      acc=fmaf(x0.x,w0[0],acc); acc=fmaf(x0.y,w0[1],acc);
      acc=fmaf(x0.z,w0[2],acc); acc=fmaf(x0.w,w0[3],acc);
      acc=fmaf(x1.x,w0[4],acc); acc=fmaf(x1.y,w0[5],acc);
      acc=fmaf(x1.z,w0[6],acc); acc=fmaf(x1.w,w0[7],acc);
      acc=fmaf(x2.x,w0[8],acc); acc=fmaf(x2.y,w0[9],acc);
      acc=fmaf(x2.z,w0[10],acc); acc=fmaf(x2.w,w0[11],acc);
      Tk[R*72+lane] = (__bf16)(gelu_f(acc)*(float)mfb[R]);
    }
  }
  if (ar<15){   // ln1, own rows (shuffles stay within same-ar groups)
    int R = 15*wv + ar;
    float x[16]; load16f(Tk + R*72 + quad*16, x);
    float s=0.f;
    #pragma unroll
    for (int i=0;i<16;i++) s += x[i];
    s += __shfl_xor(s,16,64); s += __shfl_xor(s,32,64);
    float m = s*(1.f/64.f), q=0.f;
    #pragma unroll
    for (int i=0;i<16;i++){ float d=x[i]-m; q=fmaf(d,d,q); }
    q += __shfl_xor(q,16,64); q += __shfl_xor(q,32,64);
    float rs = __builtin_amdgcn_rsqf(q*(1.f/64.f)+1e-6f);
    v8bf o0,o1;
    #pragma unroll
    for (int i=0;i<8;i++){
      o0[i]=(__bf16)((x[i]  -m)*rs*a.ln1_s[quad*16+i]  +a.ln1_b[quad*16+i]);
      o1[i]=(__bf16)((x[8+i]-m)*rs*a.ln1_s[quad*16+8+i]+a.ln1_b[quad*16+8+i]);
    }
    *(v8bf*)(Ab+R*136+quad*16)=o0; *(v8bf*)(Ab+R*136+quad*16+8)=o1;
  }
  BAR();   // S1

  auto actAb = [&](int mt,int kt,int r,int q){ return *(const v8bf*)(Ab + (size_t)(mt*16+r)*136 + q*8 + kt*32); };
  auto actBb = [&](int mt,int kt,int r,int q){ return *(const v8bf*)(Bb + (size_t)(mt*16+r)*136 + q*8 + kt*32); };
  auto actTk = [&](int mt,int kt,int r,int q){ return *(const v8bf*)(Tk + (size_t)(mt*16+r)*72  + q*8 + kt*32); };

  // ---- QKV: K -> Bb[:,64:], V -> Ab[:,64:], Q -> Bb[:,0:64] ----
  // V/Q weight loads issue up front; latency hides under K's MFMAs.
  auto wfV = wload<2,1>(ws+W_A1V, a.a1_vb, wv, lane);
  auto wfQ = wload<2,1>(ws+W_A1Q, a.a1_qb, wv, lane);
  gemmW<2,4,1>(actAb, wfK, wv, lane,
    [&](int wb,int mt,int r,v4f c){ v4bf o;
      #pragma unroll
      for (int k=0;k<4;k++) o[k]=(__bf16)c[k];
      *(v4bf*)&Bb[(mt*16+r)*136+64+wb]=o; });
  gemmW<2,4,1>(actAb, wfV, wv, lane,
    [&](int wb,int mt,int r,v4f c){ v4bf o;
      #pragma unroll
      for (int k=0;k<4;k++) o[k]=(__bf16)c[k];
      *(v4bf*)&Ab[(mt*16+r)*136+64+wb]=o; });
  gemmW<2,4,1>(actAb, wfQ, wv, lane,
    [&](int wb,int mt,int r,v4f c){ v4bf o;
      #pragma unroll
      for (int k=0;k<4;k++) o[k]=(__bf16)c[k];
      *(v4bf*)&Bb[(mt*16+r)*136+wb]=o; });
  BAR();   // S2

  // ---- attn weights + attn@V (wave-local tokens) ----
  if (lane<60){
    int tg=lane/20, rem=lane-tg*20, h=rem/5, i=rem-h*5;
    int T=3*wv+tg;
    bool mi = (float)msfb[T*5+i]>0.5f;
    float qv[16]; load16f(&Bb[(T*5+i)*136 + h*16], qv);
    float lgv[5], mx=NEG_INF_F;
    #pragma unroll
    for (int j=0;j<5;j++){
      float kk[16]; load16f(&Bb[(T*5+j)*136 + 64 + h*16], kk);
      float d=0.f;
      #pragma unroll
      for (int dd=0;dd<16;dd++) d += qv[dd]*kk[dd];
      bool mj = (float)msfb[T*5+j]>0.5f;
      lgv[j] = (mi&&mj)? d*0.25f : NEG_INF_F;
      mx = fmaxf(mx,lgv[j]);
    }
    float sum=0.f, ex[5];
    #pragma unroll
    for (int j=0;j<5;j++){ ex[j]=__expf(lgv[j]-mx); sum+=ex[j]; }
    float inv=1.0f/sum;
    #pragma unroll
    for (int j=0;j<5;j++) ATTb[T*100+(h*5+i)*5+j]=(__bf16)(ex[j]*inv);
  }
  {
    int h = lane>>4;
    #pragma unroll
    for (int tg=0; tg<3; tg++){
      int T=3*wv+tg;
      float v5[5];
      #pragma unroll
      for (int j=0;j<5;j++) v5[j] = (float)Ab[(T*5+j)*136+64+lane];
      #pragma unroll
      for (int i=0;i<5;i++){
        float o=0.f;
        #pragma unroll
        for (int j=0;j<5;j++) o += (float)ATTb[T*100+(h*5+i)*5+j]*v5[j];
        Ab[(T*5+i)*136+lane]=(__bf16)o;
      }
    }
  }
  // prefetch o-proj weights (ALL 4 N-tiles — M-split gemm) across S3
  auto wfO = wloadA<2,4>(ws+W_A1O, a.a1_ob, lane);
  BAR();   // S3

  // ---- FUSED o-proj + residual + ln2 (M-split: wave wv owns rows
  //      16wv..16wv+15, all 4 N-tiles => full row per lane-group; ln2
  //      stats via shfl_xor 16/32 — ln2 phase + barrier eliminated) ----
  {
    float4 s2[4], b2[4];   // ln2 params for cols nt*16+quad*4 .. +3
    #pragma unroll
    for (int nt=0; nt<4; nt++){
      s2[nt] = *(const float4*)(a.ln2_s + nt*16 + quad*4);
      b2[nt] = *(const float4*)(a.ln2_b + nt*16 + quad*4);
    }
    const int R = wv*16 + ar;
    const float mm = (float)mfb[R];
    float acc[16];
    #pragma unroll
    for (int nt=0; nt<4; nt++){
      v4f c; c[0]=wfO.b[nt].x; c[1]=wfO.b[nt].y; c[2]=wfO.b[nt].z; c[3]=wfO.b[nt].w;
      #pragma unroll
      for (int kt=0; kt<2; kt++)
        c = __builtin_amdgcn_mfma_f32_16x16x32_bf16(wfO.w[nt][kt], actAb(wv,kt,ar,quad), c, 0,0,0);
      v4bf old = *(const v4bf*)&Tk[R*72 + nt*16 + quad*4];
      #pragma unroll
      for (int k=0;k<4;k++) acc[nt*4+k] = (float)old[k] + c[k]*mm;
    }
    #pragma unroll
    for (int nt=0; nt<4; nt++){
      v4bf o;
      #pragma unroll
      for (int k=0;k<4;k++) o[k] = (__bf16)acc[nt*4+k];
      *(v4bf*)&Tk[R*72 + nt*16 + quad*4] = o;
    }
    float s=0.f;
    #pragma unroll
    for (int i=0;i<16;i++) s += acc[i];
    s += __shfl_xor(s,16,64); s += __shfl_xor(s,32,64);
    float m = s*(1.f/64.f), q=0.f;
    #pragma unroll
    for (int i=0;i<16;i++){ float d=acc[i]-m; q=fmaf(d,d,q); }
    q += __shfl_xor(q,16,64); q += __shfl_xor(q,32,64);
    float rs = __builtin_amdgcn_rsqf(q*(1.f/64.f)+1e-6f);
    #pragma unroll
    for (int nt=0; nt<4; nt++){
      v4bf o;
      o[0]=(__bf16)((acc[nt*4+0]-m)*rs*s2[nt].x+b2[nt].x);
      o[1]=(__bf16)((acc[nt*4+1]-m)*rs*s2[nt].y+b2[nt].y);
      o[2]=(__bf16)((acc[nt*4+2]-m)*rs*s2[nt].z+b2[nt].z);
      o[3]=(__bf16)((acc[nt*4+3]-m)*rs*s2[nt].w+b2[nt].w);
      *(v4bf*)&Ab[R*136 + nt*16 + quad*4] = o;
    }
  }
  auto wfM1 = wload<2,2>(ws+W_M1, a.m1_b, wv, lane);
  BAR();   // S4 (ln2 phase/barrier eliminated)

  // ---- m1 -> Bb[:,0:128] ----
  gemmW<2,4,2>(actAb, wfM1, wv, lane,
    [&](int wb,int mt,int r,v4f c){ v4bf o;
      #pragma unroll
      for (int k=0;k<4;k++) o[k]=(__bf16)gelu_f(c[k]);
      *(v4bf*)&Bb[(mt*16+r)*136+wb]=o; });
  auto wfM2 = wload<4,2>(ws+W_M2, a.m2_b, wv, lane);
  BAR();   // S6
  // ---- m2 -> Ab[:,0:128] ----
  gemmW<4,4,2>(actBb, wfM2, wv, lane,
    [&](int wb,int mt,int r,v4f c){ v4bf o;
      #pragma unroll
      for (int k=0;k<4;k++) o[k]=(__bf16)gelu_f(c[k]);
      *(v4bf*)&Ab[(mt*16+r)*136+wb]=o; });
  auto wfM3 = wload<4,1>(ws+W_M3, a.m3_b, wv, lane);
  auto wfE1 = wload<1,2>(ws+W_E1, a.e1_b, wv, lane);
  BAR();   // S7
  // ---- m3 -> Tk (resid*mask) ; e1 (token-level) -> Bb rows 0..15 ----
  gemmW<4,4,1>(actAb, wfM3, wv, lane,
    [&](int wb,int mt,int r,v4f c){
      int R=mt*16+r; float mm=(float)mfb[R];
      v4bf old=*(const v4bf*)&Tk[R*72+wb]; v4bf o;
      #pragma unroll
      for (int k=0;k<4;k++) o[k]=(__bf16)(((float)old[k]+c[k]*mm)*mm);
      *(v4bf*)&Tk[R*72+wb]=o; });
  gemmW<1,1,2>([&](int,int,int r,int q){ return *(const v8bf*)(Eg + (size_t)r*40 + q*8); },
    wfE1, wv, lane,
    [&](int wb,int mt,int r,v4f c){ v4bf o;
      #pragma unroll
      for (int k=0;k<4;k++) o[k]=(__bf16)gelu_f(c[k]);
      *(v4bf*)&Bb[r*136+wb]=o; });
  auto wfE2 = wload<4,2>(ws+W_E2, a.e2_b, wv, lane);
  BAR();   // S8
  // ---- e2 -> Ab rows 0..15 ----
  gemmW<4,1,2>(actBb, wfE2, wv, lane,
    [&](int wb,int mt,int r,v4f c){ v4bf o;
      #pragma unroll
      for (int k=0;k<4;k++) o[k]=(__bf16)gelu_f(c[k]);
      *(v4bf*)&Ab[r*136+wb]=o; });
  auto wfE3 = wload<4,1>(ws+W_E3, a.e3_b, wv, lane);
  BAR();   // S9
  // ---- e3 -> ECX rows 0..15 ----
  gemmW<4,1,1>(actAb, wfE3, wv, lane,
    [&](int wb,int mt,int r,v4f c){ v4bf o;
      #pragma unroll
      for (int k=0;k<4;k++) o[k]=(__bf16)c[k];
      *(v4bf*)&ECX[r*64+wb]=o; });
  auto wfL1 = wload<4,2>(ws+W_L1, a.l1_b, wv, lane);
  BAR();   // S10
  // ---- l1 (act = [Tk | ECX(token)]) -> Bb[:,0:128] ----
  gemmW<4,4,2>([&](int mt,int kt,int r,int q){
      int R=mt*16+r;
      return (kt<2) ? *(const v8bf*)(Tk + (size_t)R*72 + q*8 + kt*32)
                    : *(const v8bf*)(ECX + (size_t)((R*205)>>10)*64 + q*8 + (kt-2)*32); },
    wfL1, wv, lane,
    [&](int wb,int mt,int r,v4f c){ v4bf o;
      #pragma unroll
      for (int k=0;k<4;k++) o[k]=(__bf16)gelu_f(c[k]);
      *(v4bf*)&Bb[(mt*16+r)*136+wb]=o; });
  auto wfL2 = wload<4,2>(ws+W_L2, a.l2_b, wv, lane);
  BAR();   // S11
  // ---- l2 -> Ab[:,0:128] ----
  gemmW<4,4,2>(actBb, wfL2, wv, lane,
    [&](int wb,int mt,int r,v4f c){ v4bf o;
      #pragma unroll
      for (int k=0;k<4;k++) o[k]=(__bf16)gelu_f(c[k]);
      *(v4bf*)&Ab[(mt*16+r)*136+wb]=o; });
  auto wfPK = wload<2,1>(ws+W_PK, a.p_kb, wv, lane);
  auto wfPV = wload<2,1>(ws+W_PV, a.p_vb, wv, lane);
  BAR();   // S12

  // ---- l3 (own rows) + alpha + v_r/v_u ; kp/vp -> Bb ----
  if (ar<15){
    int R = 15*wv + ar;
    float x[16], y[16];
    load16f(&Ab[R*136 + quad*32], x);
    load16f(&Ab[R*136 + quad*32 + 16], y);
    const float* w = a.l3_w + quad*32;
    float p = 0.f;
    #pragma unroll
    for (int i=0;i<16;i++) p = fmaf(x[i], w[i], p);
    #pragma unroll
    for (int i=0;i<16;i++) p = fmaf(y[i], w[16+i], p);
    p += __shfl_xor(p,16,64); p += __shfl_xor(p,32,64);
    if (quad==0) lga[R] = p + a.l3_b[0];
  }
  gemmW<2,4,1>(actTk, wfPK, wv, lane,
    [&](int wb,int mt,int r,v4f c){ v4bf o;
      #pragma unroll
      for (int k=0;k<4;k++) o[k]=(__bf16)c[k];
      *(v4bf*)&Bb[(mt*16+r)*136+wb]=o; });
  gemmW<2,4,1>(actTk, wfPV, wv, lane,
    [&](int wb,int mt,int r,v4f c){ v4bf o;
      #pragma unroll
      for (int k=0;k<4;k++) o[k]=(__bf16)c[k];
      *(v4bf*)&Bb[(mt*16+r)*136+64+wb]=o; });
  if (lane<3){
    int T=3*wv+lane;
    float ml[5], mx=-1e9f;
    #pragma unroll
    for (int i=0;i<5;i++){ ml[i]=((float)mfb[T*5+i]>0.5f)? lga[T*5+i] : -1e9f; mx=fmaxf(mx,ml[i]); }
    float den=0.f, e[5];
    #pragma unroll
    for (int i=0;i<5;i++){ e[i]=__expf(ml[i]-mx)*(float)mfb[T*5+i]; den+=e[i]; }
    float inv=1.0f/(den+1e-9f);
    #pragma unroll
    for (int i=0;i<5;i++) lga[T*5+i]=e[i]*inv;
  }
  if (lane<18){
    int tg=lane/6, c=lane-tg*6;
    int T=3*wv+tg;
    float v=0.f;
    #pragma unroll
    for (int i=0;i<5;i++) v += lga[T*5+i]*(float)Ru[T*30+i*6+c];
    long tk = blkT0 + T;
    if (tk<ntok) a.out[tk*134+128+c]=v;
  }
  BAR();   // S13

  // ---- pooling attn + pooled-o (wave-local tokens) ----
  if (lane<12){
    const float* qg = (const float*)(ws + W_QP);
    int tg=lane>>2, h=lane&3;
    int T=3*wv+tg;
    float qv[16];
    #pragma unroll
    for (int dd=0;dd<16;dd++) qv[dd]=qg[h*16+dd];
    float lgv[5], mx=NEG_INF_F;
    #pragma unroll
    for (int j=0;j<5;j++){
      float kk[16]; load16f(&Bb[(T*5+j)*136 + h*16], kk);
      float d=0.f;
      #pragma unroll
      for (int dd=0;dd<16;dd++) d += qv[dd]*kk[dd];
      lgv[j] = ((float)msfb[T*5+j]>0.5f)? d*0.25f : NEG_INF_F;
      mx = fmaxf(mx,lgv[j]);
    }
    float sum=0.f, ex[5];
    #pragma unroll
    for (int j=0;j<5;j++){ ex[j]=__expf(lgv[j]-mx); sum+=ex[j]; }
    float inv=1.0f/sum;
    #pragma unroll
    for (int j=0;j<5;j++) pattn[T*20+h*5+j]=ex[j]*inv;
  }
  for (int it=lane; it<192; it+=64){
    int tg=it>>6, c=it&63, h=c>>4;
    int T=3*wv+tg;
    float o=0.f;
    #pragma unroll
    for (int j=0;j<5;j++)
      o += pattn[T*20+h*5+j]*(float)Bb[(T*5+j)*136+64+c];
    Po[T*64+c]=(__bf16)o;
  }
  auto wfPO = wload<2,1>(ws+W_PO, a.p_ob, wv, lane);
  BAR();   // S14

  // ---- p_ow -> Cc (x many) ----
  gemmW<2,1,1>([&](int,int kt,int r,int q){ return *(const v8bf*)(Po + (size_t)r*64 + q*8 + kt*32); },
    wfPO, wv, lane,
    [&](int wb,int mt,int r,v4f c){
      float mm = many[r];
      v4bf o;
      #pragma unroll
      for (int k=0;k<4;k++) o[k]=(__bf16)(c[k]*mm);
      *(v4bf*)&Cc[r*64+wb]=o; });
  auto wfH1 = wload<5,2>(ws+W_H1, a.h1_b, wv, lane);
  BAR();   // S15

  // ---- h1 (act = [Eg | Cc | Pe], K=160) -> Bb rows 0..15 ----
  gemmW<5,1,2>([&](int,int kt,int r,int q){
      if (kt==0) return *(const v8bf*)(Eg + (size_t)r*40 + q*8);
      if (kt<3)  return *(const v8bf*)(Cc + (size_t)r*64 + q*8 + (kt-1)*32);
      return *(const v8bf*)(Pe + (size_t)r*64 + q*8 + (kt-3)*32); },
    wfH1, wv, lane,
    [&](int wb,int mt,int r,v4f c){ v4bf o;
      #pragma unroll
      for (int k=0;k<4;k++) o[k]=(__bf16)gelu_f(c[k]);
      *(v4bf*)&Bb[r*136+wb]=o; });
  auto wfH2 = wload<4,2>(ws+W_H2, a.h2_b, wv, lane);
  BAR();   // S16
  // ---- h2 -> Ab rows 0..15 ----
  gemmW<4,1,2>(actBb, wfH2, wv, lane,
    [&](int wb,int mt,int r,v4f c){ v4bf o;
      #pragma unroll
      for (int k=0;k<4;k++) o[k]=(__bf16)gelu_f(c[k]);
      *(v4bf*)&Ab[r*136+wb]=o; });
  auto wfH3 = wload<4,2>(ws+W_H3, a.h3_b, wv, lane);
  BAR();   // S17
  // ---- h3 -> out ----
  gemmW<4,1,2>(actAb, wfH3, wv, lane,
    [&](int wb,int mt,int r,v4f c){
      long tk = blkT0 + r;
      if (r<12 && tk<ntok){
        float2* o2 = (float2*)&a.out[tk*134 + wb];
        o2[0] = make_float2(c[0], c[1]);
        o2[1] = make_float2(c[2], c[3]);
      } });
}

extern "C" void kernel_launch(void* const* d_in, const int* in_sizes, int n_in,
                              void* d_out, int out_size, void* d_ws, size_t ws_size,
                              hipStream_t stream)
{
  P a;
  const float** pp = reinterpret_cast<const float**>(&a);
  for (int i=0;i<50;i++) pp[i] = reinterpret_cast<const float*>(d_in[i]);
  a.out = reinterpret_cast<float*>(d_out);
  int ntok = in_sizes[0] / DOBS;   // 65536

  __bf16* ws = reinterpret_cast<__bf16*>(d_ws);
  hipLaunchKernelGGL(prep_w, dim3(173), dim3(256), 0, stream, a, ws);
  hipLaunchKernelGGL(swarm_mfma, dim3((ntok+11)/12), dim3(256), 0, stream, a, ws, ntok);
}

// Round 10
// 493.150 us; speedup vs baseline: 1.0136x; 1.0136x over previous
//
#include <hip/hip_runtime.h>
#include <math.h>

// SwarmSetEquivariantTorso — bf16 MFMA, N-split block GEMMs, 12 tok/block.
// HISTORY: R0 375us | R5 act-reuse+weight-batch 463us (batching = poison)
// R7 8tok/4blk 437us (occupancy not the lever) | R8 361us (WIN: weight
// prefetch across non-draining BAR()) | R9 ln2-fusion 363.6us (NEUTRAL:
// phase count not the lever -> reverted).
// THIS = R8 + act-read reuse ONLY (de-confounded R5 positive):
//  (1) gemmW loop order mt->kt->ln with c[NTPW] accumulators: one act
//      ds_read_b128 feeds all of a wave's N-tiles;
//  (2) QKV fused via gemmF (3 weight sets share each act read); PK/PV
//      fused (2 sets). Weights still prefetched across the preceding
//      barrier per R8 — no up-front global batching on the crit path.
// ~116 redundant b128 reads/wave removed; R5 measured conflicts 28.6M->18M.

#define DOBS 198
#define NEG_INF_F (-3.402823466e38f)

// Non-draining barrier: LDS visibility via lgkmcnt(0); global (weight)
// loads stay in flight. No cross-wave global communication in-kernel.
#define BAR() do { asm volatile("s_waitcnt lgkmcnt(0)" ::: "memory"); \
                   __builtin_amdgcn_s_barrier(); } while(0)

typedef __bf16 v8bf __attribute__((ext_vector_type(8)));
typedef __bf16 v4bf __attribute__((ext_vector_type(4)));
typedef float  v4f  __attribute__((ext_vector_type(4)));

struct P {
  const float *obs,*tok_w,*tok_b,*ln1_s,*ln1_b,
    *a1_qw,*a1_qb,*a1_kw,*a1_kb,*a1_vw,*a1_vb,*a1_ow,*a1_ob,
    *ln2_s,*ln2_b,*m1_w,*m1_b,*m2_w,*m2_b,*m3_w,*m3_b,
    *e1_w,*e1_b,*e2_w,*e2_b,*e3_w,*e3_b,
    *l1_w,*l1_b,*l2_w,*l2_b,*l3_w,*l3_b,
    *seed,*p_qw,*p_qb,*p_kw,*p_kb,*p_vw,*p_vb,*p_ow,*p_ob,
    *pr_w,*pr_b,*h1_w,*h1_b,*h2_w,*h2_b,*h3_w,*h3_b;
  float* out;
};
static_assert(sizeof(P) == 51*sizeof(void*), "P layout");

// ws bf16 weight image, W_t[n][k] per matrix (element offsets)
#define W_A1Q 0
#define W_A1K 4096
#define W_A1V 8192
#define W_A1O 12288
#define W_M1  16384
#define W_M2  24576
#define W_M3  40960
#define W_E1  49152
#define W_E2  53248
#define W_E3  69632
#define W_L1  77824
#define W_L2  94208
#define W_PK  110592
#define W_PV  114688
#define W_PO  118784
#define W_H1  122880
#define W_H2  143360
#define W_H3  159744
#define W_END 176128
#define W_QP  176128   // + 64 f32 (pooling query, precomputed)

__global__ __launch_bounds__(256)
void prep_w(P a, __bf16* ws)
{
  if (blockIdx.x == 172){
    int t = threadIdx.x;
    if (t < 64){
      float acc = a.p_qb[t];
      for (int k=0;k<64;k++) acc += a.seed[k]*a.p_qw[k*64+t];
      ((float*)(ws + W_QP))[t] = acc;
    }
    return;
  }
  const float* srcs[18] = {a.a1_qw,a.a1_kw,a.a1_vw,a.a1_ow,a.m1_w,a.m2_w,a.m3_w,
                           a.e1_w,a.e2_w,a.e3_w,a.l1_w,a.l2_w,a.p_kw,a.p_vw,a.p_ow,
                           a.h1_w,a.h2_w,a.h3_w};
  const int Ks[18]   = {64,64,64,64,64,128,128,32,128,128,128,128,64,64,64,160,128,128};
  const int Ns[18]   = {64,64,64,64,128,128,64,128,128,64,128,128,64,64,64,128,128,128};
  const int offs[18] = {W_A1Q,W_A1K,W_A1V,W_A1O,W_M1,W_M2,W_M3,W_E1,W_E2,W_E3,
                        W_L1,W_L2,W_PK,W_PV,W_PO,W_H1,W_H2,W_H3};
  __shared__ float tile[32][33];
  int b = blockIdx.x, m = 0, acc = 0;
  for (; m < 18; m++){
    int t = (Ks[m]/32)*(Ns[m]/32);
    if (b < acc + t) break;
    acc += t;
  }
  int lt = b - acc, K = Ks[m], N = Ns[m];
  int ntile = N/32, kt = lt/ntile, nt = lt%ntile;
  int tx = threadIdx.x & 31, ty = threadIdx.x >> 5;
  const float* S = srcs[m];
  #pragma unroll
  for (int rr=0; rr<32; rr+=8)
    tile[ty+rr][tx] = S[(size_t)(kt*32+ty+rr)*N + nt*32+tx];
  __syncthreads();
  __bf16* D = ws + offs[m];
  #pragma unroll
  for (int rr=0; rr<32; rr+=8)
    D[(size_t)(nt*32+ty+rr)*K + kt*32+tx] = (__bf16)tile[tx][ty+rr];
}

// gelu(x) = x * sigmoid(2t),  t = 0.79788456(x + 0.044715 x^3)  (exact tanh form)
__device__ __forceinline__ float gelu_f(float x){
  float t = x * fmaf(0.0356774081f, x*x, 0.7978845608f);
  float u = __builtin_amdgcn_exp2f(-2.885390082f * t);
  return x * __builtin_amdgcn_rcpf(1.0f + u);
}

__device__ __forceinline__ void load16f(const __bf16* p, float* f){
  v8bf a = *(const v8bf*)p, b = *(const v8bf*)(p+8);
  #pragma unroll
  for (int i=0;i<8;i++){ f[i]=(float)a[i]; f[8+i]=(float)b[i]; }
}

// Weight fragments, issued early (prefetch), consumed after next barrier.
template<int KT,int NTPW> struct WF {
  v8bf  w[NTPW][KT];
  float4 b[NTPW];
};

// N-split loader: wave wv's NTPW consecutive N-tiles of one matrix.
template<int KT,int NTPW>
__device__ __forceinline__ WF<KT,NTPW> wload(const __bf16* __restrict__ Wt,
    const float* __restrict__ bias, int wv, int lane)
{
  WF<KT,NTPW> f;
  const int ar = lane&15, quad = lane>>4;
  #pragma unroll
  for (int ln=0; ln<NTPW; ln++){
    const int wt = wv*NTPW + ln;
    const __bf16* wp = Wt + (size_t)(wt*16+ar)*(KT*32) + quad*8;
    #pragma unroll
    for (int kt=0;kt<KT;kt++) f.w[ln][kt] = *(const v8bf*)(wp + kt*32);
    f.b[ln] = *(const float4*)(bias + wt*16 + quad*4);
  }
  return f;
}

// Fused-matrix loader: wave wv's N-tile (tile index wv) of NW matrices.
template<int KT,int NW>
__device__ __forceinline__ WF<KT,NW> wloadF(const __bf16* const* Ws,
    const float* const* bs, int wv, int lane)
{
  WF<KT,NW> f;
  const int ar = lane&15, quad = lane>>4;
  #pragma unroll
  for (int w=0; w<NW; w++){
    const __bf16* wp = Ws[w] + (size_t)(wv*16+ar)*(KT*32) + quad*8;
    #pragma unroll
    for (int kt=0;kt<KT;kt++) f.w[w][kt] = *(const v8bf*)(wp + kt*32);
    f.b[w] = *(const float4*)(bs[w] + wv*16 + quad*4);
  }
  return f;
}

// N-split GEMM, act-reuse order: one act read per (mt,kt) feeds all NTPW
// N-tile accumulators. Weights already in regs (prefetched).
template<int KT,int MT,int NTPW,typename LA,typename E>
__device__ __forceinline__ void gemmW(LA la, const WF<KT,NTPW>& f,
    int wv, int lane, E epi)
{
  const int ar = lane&15, quad = lane>>4;
  #pragma unroll
  for (int mt=0; mt<MT; mt++){
    v4f c[NTPW];
    #pragma unroll
    for (int ln=0;ln<NTPW;ln++){
      c[ln][0]=f.b[ln].x; c[ln][1]=f.b[ln].y; c[ln][2]=f.b[ln].z; c[ln][3]=f.b[ln].w;
    }
    #pragma unroll
    for (int kt=0;kt<KT;kt++){
      v8bf av = la(mt,kt,ar,quad);
      #pragma unroll
      for (int ln=0;ln<NTPW;ln++)
        c[ln] = __builtin_amdgcn_mfma_f32_16x16x32_bf16(f.w[ln][kt], av, c[ln], 0,0,0);
    }
    #pragma unroll
    for (int ln=0;ln<NTPW;ln++)
      epi((wv*NTPW+ln)*16 + quad*4, mt, ar, c[ln]);
  }
}

// Fused-matrix GEMM: one act read per (mt,kt) feeds NW matrices' tiles.
// epi(w, wb, mt, ar, c) — wb = wv*16+quad*4 within matrix w.
template<int KT,int MT,int NW,typename LA,typename E>
__device__ __forceinline__ void gemmF(LA la, const WF<KT,NW>& f,
    int wv, int lane, E epi)
{
  const int ar = lane&15, quad = lane>>4;
  #pragma unroll
  for (int mt=0; mt<MT; mt++){
    v4f c[NW];
    #pragma unroll
    for (int w=0;w<NW;w++){
      c[w][0]=f.b[w].x; c[w][1]=f.b[w].y; c[w][2]=f.b[w].z; c[w][3]=f.b[w].w;
    }
    #pragma unroll
    for (int kt=0;kt<KT;kt++){
      v8bf av = la(mt,kt,ar,quad);
      #pragma unroll
      for (int w=0;w<NW;w++)
        c[w] = __builtin_amdgcn_mfma_f32_16x16x32_bf16(f.w[w][kt], av, c[w], 0,0,0);
    }
    #pragma unroll
    for (int w=0;w<NW;w++)
      epi(w, wv*16 + quad*4, mt, ar, c[w]);
  }
}

// LDS map (bytes), total 53120 <= 53248 (proven 3 blocks/CU):
//  Ab   @0      bf16[64][136] 17408  (early: Df f32[12][32])
//  Bb   @17408  bf16[64][136] 17408  (early: TOKIN f32[60][12])
//  Tk   @34816  bf16[64][72]   9216  (early: OBSf f32[12][120]; late: Po bf16[12][64])
//  Pe   @44032  bf16[16][64]   2048
//  Eg   @46080  bf16[16][40]   1280
//  Ru   @47360  bf16[12][30]    736
//  mfb  @48096  bf16[64]        128
//  msfb @48224  bf16[64]        128
//  many @48352  f32[16]          64
//  lga  @48416  f32[64]         256
//  ECX  @48672  bf16[16][64]   2048  (late: pattn f32[12][20])
//  ATTb @50720  bf16[12][100]  2400  (late: Cc bf16[16][64])
__global__ __launch_bounds__(256,3)
void swarm_mfma(P a, const __bf16* __restrict__ ws, int ntok)
{
  __shared__ char smem[53120] __attribute__((aligned(16)));
  __bf16* Ab   = (__bf16*)(smem);
  __bf16* Bb   = (__bf16*)(smem+17408);
  float*  TOKIN= (float*) (smem+17408);
  __bf16* Tk   = (__bf16*)(smem+34816);
  float*  OBSf = (float*) (smem+34816);
  __bf16* Po   = (__bf16*)(smem+34816);
  __bf16* Pe   = (__bf16*)(smem+44032);
  __bf16* Eg   = (__bf16*)(smem+46080);
  __bf16* Ru   = (__bf16*)(smem+47360);
  __bf16* mfb  = (__bf16*)(smem+48096);
  __bf16* msfb = (__bf16*)(smem+48224);
  float*  many = (float*) (smem+48352);
  float*  lga  = (float*) (smem+48416);
  __bf16* ECX  = (__bf16*)(smem+48672);
  float*  pattn= (float*) (smem+48672);
  __bf16* ATTb = (__bf16*)(smem+50720);
  __bf16* Cc   = (__bf16*)(smem+50720);

  const int lane = threadIdx.x & 63;
  const int wv   = threadIdx.x >> 6;
  const int ar   = lane & 15, quad = lane >> 4;
  const long blkT0 = (long)blockIdx.x*12;

  // ================= setup (wave-local tokens 3wv..3wv+2) =================
  for (int it=lane; it<3*117; it+=64){
    int tg=it/117, c=it-tg*117;
    long gt = blkT0 + 3*wv + tg; if (gt>ntok-1) gt=ntok-1;
    OBSf[(3*wv+tg)*120+c] = a.obs[gt*DOBS+c];
  }
  float* Df = (float*)Ab;
  for (int it=lane; it<75; it+=64){
    int tg=it/25, p=it-tg*25, i=p/5, j=p-i*5;
    const float* ob = OBSf + (3*wv+tg)*120 + 32;
    float d2=0.f;
    #pragma unroll
    for (int d=0;d<3;d++){
      float ri=ob[15*i+d]; ri = isfinite(ri)?ri:0.f;
      float rj=ob[15*j+d]; rj = isfinite(rj)?rj:0.f;
      float df=ri-rj; d2 += df*df;
    }
    Df[(3*wv+tg)*32+p]=sqrtf(d2);
  }
  if (lane<15){
    int T=3*wv+lane/5, s=lane%5;
    const float* b = OBSf + T*120 + 32 + 15*s;
    mfb[15*wv+lane] = (__bf16)((fabsf(b[0])>1e-6f||fabsf(b[1])>1e-6f||fabsf(b[2])>1e-6f)?1.f:0.f);
  }
  if (wv==0 && lane>=60){ mfb[lane]=(__bf16)0.f; msfb[lane]=(__bf16)0.f; }
  if (wv==0 && lane>=12 && lane<16) many[lane]=0.f;
  if (lane<3){
    int T=3*wv+lane;
    float any = (float)mfb[T*5]+(float)mfb[T*5+1]+(float)mfb[T*5+2]+(float)mfb[T*5+3]+(float)mfb[T*5+4];
    float anyf = (any>0.f)?1.f:0.f; many[T]=anyf;
    #pragma unroll
    for (int i=0;i<5;i++) msfb[T*5+i] = (anyf>0.f)? mfb[T*5+i] : (__bf16)((i==0)?1.f:0.f);
  }
  if (lane<15){
    int T=3*wv+lane/5, i=lane%5, R=15*wv+lane;
    float dmin=1e9f,dsum=0.f,cnt=0.f;
    #pragma unroll
    for (int j=0;j<5;j++){
      if (j!=i && (float)mfb[T*5+i]>0.5f && (float)mfb[T*5+j]>0.5f){
        float dd=Df[T*32+i*5+j];
        dmin=fminf(dmin,dd); dsum+=dd; cnt+=1.f;
      }
    }
    TOKIN[R*12+10]=dmin;
    TOKIN[R*12+11]=(cnt>0.f)? dsum/(cnt+1e-9f) : 0.f;
  }
  for (int it=lane; it<150; it+=64){
    int tg=it/50, q=it-tg*50, s=q/10, c=q-s*10;
    int T=3*wv+tg;
    const float* b = OBSf + T*120 + 32 + 15*s;
    float v;
    if (c<4)        v=b[11+c];
    else if (c==4)  v=b[9];
    else if (c==5)  v=b[10];
    else if (c<9)   v=b[6+(c-6)];
    else { float a0=b[6],a1=b[7],a2=b[8]; v=sqrtf(a0*a0+a1*a1+a2*a2); }
    TOKIN[(T*5+s)*12+c]=v;
  }
  for (int it=lane; it<96; it+=64){
    int tg=it>>5, c=it&31;
    Eg[(3*wv+tg)*40+c] = (__bf16)OBSf[(3*wv+tg)*120+c];
  }
  for (int it=lane; it<90; it+=64){
    int tg=it/30, c=it-tg*30;
    Ru[(3*wv+tg)*30+c] = (__bf16)OBSf[(3*wv+tg)*120+32+15*(c/6)+(c%6)];
  }
  for (int it=lane; it<192; it+=64){
    int tg=it>>6, c=it&63;
    float acc = a.pr_b[c];
    #pragma unroll
    for (int k=0;k<10;k++) acc += OBSf[(3*wv+tg)*120+107+k]*a.pr_w[k*64+c];
    Pe[(3*wv+tg)*64+c] = (__bf16)gelu_f(acc);
  }
  BAR();   // S0: OBSf/Df/TOKIN producers done; Tk writes may begin

  // prefetch QKV weights (fused: 3 matrices, this wave's N-tile of each);
  // loads overlap tok-embed + ln1 and cross S1.
  const __bf16* WsQKV[3] = {ws+W_A1K, ws+W_A1V, ws+W_A1Q};
  const float*  bsQKV[3] = {a.a1_kb, a.a1_vb, a.a1_qb};
  auto wfQKV = wloadF<2,3>(WsQKV, bsQKV, wv, lane);

  // ---- P3: tok embed (fp32 K=12) -> Tk rows 15wv..15wv+14; then ln1 -> Ab ----
  {
    float w0[12];
    #pragma unroll
    for (int k=0;k<12;k++) w0[k] = a.tok_w[k*64+lane];
    float tb = a.tok_b[lane];
    for (int r=0;r<15;r++){
      int R = 15*wv + r;
      const float4* tin = (const float4*)(TOKIN + R*12);
      float4 x0 = tin[0], x1 = tin[1], x2 = tin[2];
      float acc = tb;
      acc=fmaf(x0.x,w0[0],acc); acc=fmaf(x0.y,w0[1],acc);
      acc=fmaf(x0.z,w0[2],acc); acc=fmaf(x0.w,w0[3],acc);
      acc=fmaf(x1.x,w0[4],acc); acc=fmaf(x1.y,w0[5],acc);
      acc=fmaf(x1.z,w0[6],acc); acc=fmaf(x1.w,w0[7],acc);
      acc=fmaf(x2.x,w0[8],acc); acc=fmaf(x2.y,w0[9],acc);
      acc=fmaf(x2.z,w0[10],acc); acc=fmaf(x2.w,w0[11],acc);
      Tk[R*72+lane] = (__bf16)(gelu_f(acc)*(float)mfb[R]);
    }
  }
  if (ar<15){   // ln1, own rows (shuffles stay within same-ar groups)
    int R = 15*wv + ar;
    float x[16]; load16f(Tk + R*72 + quad*16, x);
    float s=0.f;
    #pragma unroll
    for (int i=0;i<16;i++) s += x[i];
    s += __shfl_xor(s,16,64); s += __shfl_xor(s,32,64);
    float m = s*(1.f/64.f), q=0.f;
    #pragma unroll
    for (int i=0;i<16;i++){ float d=x[i]-m; q=fmaf(d,d,q); }
    q += __shfl_xor(q,16,64); q += __shfl_xor(q,32,64);
    float rs = __builtin_amdgcn_rsqf(q*(1.f/64.f)+1e-6f);
    v8bf o0,o1;
    #pragma unroll
    for (int i=0;i<8;i++){
      o0[i]=(__bf16)((x[i]  -m)*rs*a.ln1_s[quad*16+i]  +a.ln1_b[quad*16+i]);
      o1[i]=(__bf16)((x[8+i]-m)*rs*a.ln1_s[quad*16+8+i]+a.ln1_b[quad*16+8+i]);
    }
    *(v8bf*)(Ab+R*136+quad*16)=o0; *(v8bf*)(Ab+R*136+quad*16+8)=o1;
  }
  BAR();   // S1

  auto actAb = [&](int mt,int kt,int r,int q){ return *(const v8bf*)(Ab + (size_t)(mt*16+r)*136 + q*8 + kt*32); };
  auto actBb = [&](int mt,int kt,int r,int q){ return *(const v8bf*)(Bb + (size_t)(mt*16+r)*136 + q*8 + kt*32); };
  auto actTk = [&](int mt,int kt,int r,int q){ return *(const v8bf*)(Tk + (size_t)(mt*16+r)*72  + q*8 + kt*32); };

  // ---- QKV fused (one act read feeds K,V,Q): K -> Bb[:,64:], V -> Ab[:,64:],
  //      Q -> Bb[:,0:64] ----
  gemmF<2,4,3>(actAb, wfQKV, wv, lane,
    [&](int w,int wb,int mt,int r,v4f c){ v4bf o;
      #pragma unroll
      for (int k=0;k<4;k++) o[k]=(__bf16)c[k];
      __bf16* d = (w==0)? &Bb[(mt*16+r)*136+64+wb]
               : (w==1)? &Ab[(mt*16+r)*136+64+wb]
                       : &Bb[(mt*16+r)*136+wb];
      *(v4bf*)d = o; });
  auto wfO = wload<2,1>(ws+W_A1O, a.a1_ob, wv, lane);   // survives S2+S3
  BAR();   // S2

  // ---- attn weights + attn@V (wave-local tokens) ----
  if (lane<60){
    int tg=lane/20, rem=lane-tg*20, h=rem/5, i=rem-h*5;
    int T=3*wv+tg;
    bool mi = (float)msfb[T*5+i]>0.5f;
    float qv[16]; load16f(&Bb[(T*5+i)*136 + h*16], qv);
    float lgv[5], mx=NEG_INF_F;
    #pragma unroll
    for (int j=0;j<5;j++){
      float kk[16]; load16f(&Bb[(T*5+j)*136 + 64 + h*16], kk);
      float d=0.f;
      #pragma unroll
      for (int dd=0;dd<16;dd++) d += qv[dd]*kk[dd];
      bool mj = (float)msfb[T*5+j]>0.5f;
      lgv[j] = (mi&&mj)? d*0.25f : NEG_INF_F;
      mx = fmaxf(mx,lgv[j]);
    }
    float sum=0.f, ex[5];
    #pragma unroll
    for (int j=0;j<5;j++){ ex[j]=__expf(lgv[j]-mx); sum+=ex[j]; }
    float inv=1.0f/sum;
    #pragma unroll
    for (int j=0;j<5;j++) ATTb[T*100+(h*5+i)*5+j]=(__bf16)(ex[j]*inv);
  }
  {
    int h = lane>>4;
    #pragma unroll
    for (int tg=0; tg<3; tg++){
      int T=3*wv+tg;
      float v5[5];
      #pragma unroll
      for (int j=0;j<5;j++) v5[j] = (float)Ab[(T*5+j)*136+64+lane];
      #pragma unroll
      for (int i=0;i<5;i++){
        float o=0.f;
        #pragma unroll
        for (int j=0;j<5;j++) o += (float)ATTb[T*100+(h*5+i)*5+j]*v5[j];
        Ab[(T*5+i)*136+lane]=(__bf16)o;
      }
    }
  }
  BAR();   // S3

  // ---- o-proj + residual -> Tk (col-slices) ----
  gemmW<2,4,1>(actAb, wfO, wv, lane,
    [&](int wb,int mt,int r,v4f c){
      int R=mt*16+r; float mm=(float)mfb[R];
      v4bf old=*(const v4bf*)&Tk[R*72+wb]; v4bf o;
      #pragma unroll
      for (int k=0;k<4;k++) o[k]=(__bf16)((float)old[k]+c[k]*mm);
      *(v4bf*)&Tk[R*72+wb]=o; });
  auto wfM1 = wload<2,2>(ws+W_M1, a.m1_b, wv, lane);    // survives S4+S5
  BAR();   // S4

  // ---- ln2 -> Ab[:,0:64] (own rows) ----
  if (ar<15){
    int R = 15*wv + ar;
    float x[16]; load16f(Tk + R*72 + quad*16, x);
    float s=0.f;
    #pragma unroll
    for (int i=0;i<16;i++) s += x[i];
    s += __shfl_xor(s,16,64); s += __shfl_xor(s,32,64);
    float m = s*(1.f/64.f), q=0.f;
    #pragma unroll
    for (int i=0;i<16;i++){ float d=x[i]-m; q=fmaf(d,d,q); }
    q += __shfl_xor(q,16,64); q += __shfl_xor(q,32,64);
    float rs = __builtin_amdgcn_rsqf(q*(1.f/64.f)+1e-6f);
    v8bf o0,o1;
    #pragma unroll
    for (int i=0;i<8;i++){
      o0[i]=(__bf16)((x[i]  -m)*rs*a.ln2_s[quad*16+i]  +a.ln2_b[quad*16+i]);
      o1[i]=(__bf16)((x[8+i]-m)*rs*a.ln2_s[quad*16+8+i]+a.ln2_b[quad*16+8+i]);
    }
    *(v8bf*)(Ab+R*136+quad*16)=o0; *(v8bf*)(Ab+R*136+quad*16+8)=o1;
  }
  BAR();   // S5

  // ---- m1 -> Bb[:,0:128] ----
  gemmW<2,4,2>(actAb, wfM1, wv, lane,
    [&](int wb,int mt,int r,v4f c){ v4bf o;
      #pragma unroll
      for (int k=0;k<4;k++) o[k]=(__bf16)gelu_f(c[k]);
      *(v4bf*)&Bb[(mt*16+r)*136+wb]=o; });
  auto wfM2 = wload<4,2>(ws+W_M2, a.m2_b, wv, lane);
  BAR();   // S6
  // ---- m2 -> Ab[:,0:128] ----
  gemmW<4,4,2>(actBb, wfM2, wv, lane,
    [&](int wb,int mt,int r,v4f c){ v4bf o;
      #pragma unroll
      for (int k=0;k<4;k++) o[k]=(__bf16)gelu_f(c[k]);
      *(v4bf*)&Ab[(mt*16+r)*136+wb]=o; });
  auto wfM3 = wload<4,1>(ws+W_M3, a.m3_b, wv, lane);
  auto wfE1 = wload<1,2>(ws+W_E1, a.e1_b, wv, lane);
  BAR();   // S7
  // ---- m3 -> Tk (resid*mask) ; e1 (token-level) -> Bb rows 0..15 ----
  gemmW<4,4,1>(actAb, wfM3, wv, lane,
    [&](int wb,int mt,int r,v4f c){
      int R=mt*16+r; float mm=(float)mfb[R];
      v4bf old=*(const v4bf*)&Tk[R*72+wb]; v4bf o;
      #pragma unroll
      for (int k=0;k<4;k++) o[k]=(__bf16)(((float)old[k]+c[k]*mm)*mm);
      *(v4bf*)&Tk[R*72+wb]=o; });
  gemmW<1,1,2>([&](int,int,int r,int q){ return *(const v8bf*)(Eg + (size_t)r*40 + q*8); },
    wfE1, wv, lane,
    [&](int wb,int mt,int r,v4f c){ v4bf o;
      #pragma unroll
      for (int k=0;k<4;k++) o[k]=(__bf16)gelu_f(c[k]);
      *(v4bf*)&Bb[r*136+wb]=o; });
  auto wfE2 = wload<4,2>(ws+W_E2, a.e2_b, wv, lane);
  BAR();   // S8
  // ---- e2 -> Ab rows 0..15 ----
  gemmW<4,1,2>(actBb, wfE2, wv, lane,
    [&](int wb,int mt,int r,v4f c){ v4bf o;
      #pragma unroll
      for (int k=0;k<4;k++) o[k]=(__bf16)gelu_f(c[k]);
      *(v4bf*)&Ab[r*136+wb]=o; });
  auto wfE3 = wload<4,1>(ws+W_E3, a.e3_b, wv, lane);
  BAR();   // S9
  // ---- e3 -> ECX rows 0..15 ----
  gemmW<4,1,1>(actAb, wfE3, wv, lane,
    [&](int wb,int mt,int r,v4f c){ v4bf o;
      #pragma unroll
      for (int k=0;k<4;k++) o[k]=(__bf16)c[k];
      *(v4bf*)&ECX[r*64+wb]=o; });
  auto wfL1 = wload<4,2>(ws+W_L1, a.l1_b, wv, lane);
  BAR();   // S10
  // ---- l1 (act = [Tk | ECX(token)]) -> Bb[:,0:128] ----
  gemmW<4,4,2>([&](int mt,int kt,int r,int q){
      int R=mt*16+r;
      return (kt<2) ? *(const v8bf*)(Tk + (size_t)R*72 + q*8 + kt*32)
                    : *(const v8bf*)(ECX + (size_t)((R*205)>>10)*64 + q*8 + (kt-2)*32); },
    wfL1, wv, lane,
    [&](int wb,int mt,int r,v4f c){ v4bf o;
      #pragma unroll
      for (int k=0;k<4;k++) o[k]=(__bf16)gelu_f(c[k]);
      *(v4bf*)&Bb[(mt*16+r)*136+wb]=o; });
  auto wfL2 = wload<4,2>(ws+W_L2, a.l2_b, wv, lane);
  BAR();   // S11
  // ---- l2 -> Ab[:,0:128] ----
  gemmW<4,4,2>(actBb, wfL2, wv, lane,
    [&](int wb,int mt,int r,v4f c){ v4bf o;
      #pragma unroll
      for (int k=0;k<4;k++) o[k]=(__bf16)gelu_f(c[k]);
      *(v4bf*)&Ab[(mt*16+r)*136+wb]=o; });
  const __bf16* WsPKV[2] = {ws+W_PK, ws+W_PV};
  const float*  bsPKV[2] = {a.p_kb, a.p_vb};
  auto wfPKV = wloadF<2,2>(WsPKV, bsPKV, wv, lane);
  BAR();   // S12

  // ---- l3 (own rows) + alpha + v_r/v_u ; kp/vp fused -> Bb ----
  if (ar<15){
    int R = 15*wv + ar;
    float x[16], y[16];
    load16f(&Ab[R*136 + quad*32], x);
    load16f(&Ab[R*136 + quad*32 + 16], y);
    const float* w = a.l3_w + quad*32;
    float p = 0.f;
    #pragma unroll
    for (int i=0;i<16;i++) p = fmaf(x[i], w[i], p);
    #pragma unroll
    for (int i=0;i<16;i++) p = fmaf(y[i], w[16+i], p);
    p += __shfl_xor(p,16,64); p += __shfl_xor(p,32,64);
    if (quad==0) lga[R] = p + a.l3_b[0];
  }
  gemmF<2,4,2>(actTk, wfPKV, wv, lane,
    [&](int w,int wb,int mt,int r,v4f c){ v4bf o;
      #pragma unroll
      for (int k=0;k<4;k++) o[k]=(__bf16)c[k];
      *(v4bf*)&Bb[(mt*16+r)*136 + (w?64:0) + wb] = o; });
  if (lane<3){
    int T=3*wv+lane;
    float ml[5], mx=-1e9f;
    #pragma unroll
    for (int i=0;i<5;i++){ ml[i]=((float)mfb[T*5+i]>0.5f)? lga[T*5+i] : -1e9f; mx=fmaxf(mx,ml[i]); }
    float den=0.f, e[5];
    #pragma unroll
    for (int i=0;i<5;i++){ e[i]=__expf(ml[i]-mx)*(float)mfb[T*5+i]; den+=e[i]; }
    float inv=1.0f/(den+1e-9f);
    #pragma unroll
    for (int i=0;i<5;i++) lga[T*5+i]=e[i]*inv;
  }
  if (lane<18){
    int tg=lane/6, c=lane-tg*6;
    int T=3*wv+tg;
    float v=0.f;
    #pragma unroll
    for (int i=0;i<5;i++) v += lga[T*5+i]*(float)Ru[T*30+i*6+c];
    long tk = blkT0 + T;
    if (tk<ntok) a.out[tk*134+128+c]=v;
  }
  BAR();   // S13

  // ---- pooling attn + pooled-o (wave-local tokens) ----
  if (lane<12){
    const float* qg = (const float*)(ws + W_QP);
    int tg=lane>>2, h=lane&3;
    int T=3*wv+tg;
    float qv[16];
    #pragma unroll
    for (int dd=0;dd<16;dd++) qv[dd]=qg[h*16+dd];
    float lgv[5], mx=NEG_INF_F;
    #pragma unroll
    for (int j=0;j<5;j++){
      float kk[16]; load16f(&Bb[(T*5+j)*136 + h*16], kk);
      float d=0.f;
      #pragma unroll
      for (int dd=0;dd<16;dd++) d += qv[dd]*kk[dd];
      lgv[j] = ((float)msfb[T*5+j]>0.5f)? d*0.25f : NEG_INF_F;
      mx = fmaxf(mx,lgv[j]);
    }
    float sum=0.f, ex[5];
    #pragma unroll
    for (int j=0;j<5;j++){ ex[j]=__expf(lgv[j]-mx); sum+=ex[j]; }
    float inv=1.0f/sum;
    #pragma unroll
    for (int j=0;j<5;j++) pattn[T*20+h*5+j]=ex[j]*inv;
  }
  for (int it=lane; it<192; it+=64){
    int tg=it>>6, c=it&63, h=c>>4;
    int T=3*wv+tg;
    float o=0.f;
    #pragma unroll
    for (int j=0;j<5;j++)
      o += pattn[T*20+h*5+j]*(float)Bb[(T*5+j)*136+64+c];
    Po[T*64+c]=(__bf16)o;
  }
  auto wfPO = wload<2,1>(ws+W_PO, a.p_ob, wv, lane);
  BAR();   // S14

  // ---- p_ow -> Cc (x many) ----
  gemmW<2,1,1>([&](int,int kt,int r,int q){ return *(const v8bf*)(Po + (size_t)r*64 + q*8 + kt*32); },
    wfPO, wv, lane,
    [&](int wb,int mt,int r,v4f c){
      float mm = many[r];
      v4bf o;
      #pragma unroll
      for (int k=0;k<4;k++) o[k]=(__bf16)(c[k]*mm);
      *(v4bf*)&Cc[r*64+wb]=o; });
  auto wfH1 = wload<5,2>(ws+W_H1, a.h1_b, wv, lane);
  BAR();   // S15

  // ---- h1 (act = [Eg | Cc | Pe], K=160) -> Bb rows 0..15 ----
  gemmW<5,1,2>([&](int,int kt,int r,int q){
      if (kt==0) return *(const v8bf*)(Eg + (size_t)r*40 + q*8);
      if (kt<3)  return *(const v8bf*)(Cc + (size_t)r*64 + q*8 + (kt-1)*32);
      return *(const v8bf*)(Pe + (size_t)r*64 + q*8 + (kt-3)*32); },
    wfH1, wv, lane,
    [&](int wb,int mt,int r,v4f c){ v4bf o;
      #pragma unroll
      for (int k=0;k<4;k++) o[k]=(__bf16)gelu_f(c[k]);
      *(v4bf*)&Bb[r*136+wb]=o; });
  auto wfH2 = wload<4,2>(ws+W_H2, a.h2_b, wv, lane);
  BAR();   // S16
  // ---- h2 -> Ab rows 0..15 ----
  gemmW<4,1,2>(actBb, wfH2, wv, lane,
    [&](int wb,int mt,int r,v4f c){ v4bf o;
      #pragma unroll
      for (int k=0;k<4;k++) o[k]=(__bf16)gelu_f(c[k]);
      *(v4bf*)&Ab[r*136+wb]=o; });
  auto wfH3 = wload<4,2>(ws+W_H3, a.h3_b, wv, lane);
  BAR();   // S17
  // ---- h3 -> out ----
  gemmW<4,1,2>(actAb, wfH3, wv, lane,
    [&](int wb,int mt,int r,v4f c){
      long tk = blkT0 + r;
      if (r<12 && tk<ntok){
        float2* o2 = (float2*)&a.out[tk*134 + wb];
        o2[0] = make_float2(c[0], c[1]);
        o2[1] = make_float2(c[2], c[3]);
      } });
}

extern "C" void kernel_launch(void* const* d_in, const int* in_sizes, int n_in,
                              void* d_out, int out_size, void* d_ws, size_t ws_size,
                              hipStream_t stream)
{
  P a;
  const float** pp = reinterpret_cast<const float**>(&a);
  for (int i=0;i<50;i++) pp[i] = reinterpret_cast<const float*>(d_in[i]);
  a.out = reinterpret_cast<float*>(d_out);
  int ntok = in_sizes[0] / DOBS;   // 65536

  __bf16* ws = reinterpret_cast<__bf16*>(d_ws);
  hipLaunchKernelGGL(prep_w, dim3(173), dim3(256), 0, stream, a, ws);
  hipLaunchKernelGGL(swarm_mfma, dim3((ntok+11)/12), dim3(256), 0, stream, a, ws, ntok);
}

// Round 11
// 473.071 us; speedup vs baseline: 1.0566x; 1.0424x over previous
//
#include <hip/hip_runtime.h>
#include <math.h>

// SwarmSetEquivariantTorso — bf16 MFMA, N-split block GEMMs, 12 tok/block.
// HISTORY: R0 375us | R5 463us (weight-batch poison) | R7 437us (occupancy
// not the lever) | R8 361us (WIN: weight prefetch across non-draining BAR)
// R9 363.6us (phase-fusion NEUTRAL, reverted) | R10 354us (WIN: act-read
// reuse, one ds_read feeds all N-tiles/matrices; conflicts 28.6M->21.8M).
// THIS = R10 + attn/pool LDS-issue reduction (same family as R10):
//  - ATTb padded [T][h][32] bf16 @48672 (overlays ECX region; disjoint
//    phases): attn@V weight reads 75 scalar -> 12 v8bf per lane.
//  - pattn padded [T][h][8] f32: pooled-o reads 15 scalar -> 6 per lane.
// Attn glue was ~90 scalar LDS reads/lane ~= all GEMM act reads combined.

#define DOBS 198
#define NEG_INF_F (-3.402823466e38f)

// Non-draining barrier: LDS visibility via lgkmcnt(0); global (weight)
// loads stay in flight. No cross-wave global communication in-kernel.
#define BAR() do { asm volatile("s_waitcnt lgkmcnt(0)" ::: "memory"); \
                   __builtin_amdgcn_s_barrier(); } while(0)

typedef __bf16 v8bf __attribute__((ext_vector_type(8)));
typedef __bf16 v4bf __attribute__((ext_vector_type(4)));
typedef float  v4f  __attribute__((ext_vector_type(4)));

struct P {
  const float *obs,*tok_w,*tok_b,*ln1_s,*ln1_b,
    *a1_qw,*a1_qb,*a1_kw,*a1_kb,*a1_vw,*a1_vb,*a1_ow,*a1_ob,
    *ln2_s,*ln2_b,*m1_w,*m1_b,*m2_w,*m2_b,*m3_w,*m3_b,
    *e1_w,*e1_b,*e2_w,*e2_b,*e3_w,*e3_b,
    *l1_w,*l1_b,*l2_w,*l2_b,*l3_w,*l3_b,
    *seed,*p_qw,*p_qb,*p_kw,*p_kb,*p_vw,*p_vb,*p_ow,*p_ob,
    *pr_w,*pr_b,*h1_w,*h1_b,*h2_w,*h2_b,*h3_w,*h3_b;
  float* out;
};
static_assert(sizeof(P) == 51*sizeof(void*), "P layout");

// ws bf16 weight image, W_t[n][k] per matrix (element offsets)
#define W_A1Q 0
#define W_A1K 4096
#define W_A1V 8192
#define W_A1O 12288
#define W_M1  16384
#define W_M2  24576
#define W_M3  40960
#define W_E1  49152
#define W_E2  53248
#define W_E3  69632
#define W_L1  77824
#define W_L2  94208
#define W_PK  110592
#define W_PV  114688
#define W_PO  118784
#define W_H1  122880
#define W_H2  143360
#define W_H3  159744
#define W_END 176128
#define W_QP  176128   // + 64 f32 (pooling query, precomputed)

__global__ __launch_bounds__(256)
void prep_w(P a, __bf16* ws)
{
  if (blockIdx.x == 172){
    int t = threadIdx.x;
    if (t < 64){
      float acc = a.p_qb[t];
      for (int k=0;k<64;k++) acc += a.seed[k]*a.p_qw[k*64+t];
      ((float*)(ws + W_QP))[t] = acc;
    }
    return;
  }
  const float* srcs[18] = {a.a1_qw,a.a1_kw,a.a1_vw,a.a1_ow,a.m1_w,a.m2_w,a.m3_w,
                           a.e1_w,a.e2_w,a.e3_w,a.l1_w,a.l2_w,a.p_kw,a.p_vw,a.p_ow,
                           a.h1_w,a.h2_w,a.h3_w};
  const int Ks[18]   = {64,64,64,64,64,128,128,32,128,128,128,128,64,64,64,160,128,128};
  const int Ns[18]   = {64,64,64,64,128,128,64,128,128,64,128,128,64,64,64,128,128,128};
  const int offs[18] = {W_A1Q,W_A1K,W_A1V,W_A1O,W_M1,W_M2,W_M3,W_E1,W_E2,W_E3,
                        W_L1,W_L2,W_PK,W_PV,W_PO,W_H1,W_H2,W_H3};
  __shared__ float tile[32][33];
  int b = blockIdx.x, m = 0, acc = 0;
  for (; m < 18; m++){
    int t = (Ks[m]/32)*(Ns[m]/32);
    if (b < acc + t) break;
    acc += t;
  }
  int lt = b - acc, K = Ks[m], N = Ns[m];
  int ntile = N/32, kt = lt/ntile, nt = lt%ntile;
  int tx = threadIdx.x & 31, ty = threadIdx.x >> 5;
  const float* S = srcs[m];
  #pragma unroll
  for (int rr=0; rr<32; rr+=8)
    tile[ty+rr][tx] = S[(size_t)(kt*32+ty+rr)*N + nt*32+tx];
  __syncthreads();
  __bf16* D = ws + offs[m];
  #pragma unroll
  for (int rr=0; rr<32; rr+=8)
    D[(size_t)(nt*32+ty+rr)*K + kt*32+tx] = (__bf16)tile[tx][ty+rr];
}

// gelu(x) = x * sigmoid(2t),  t = 0.79788456(x + 0.044715 x^3)  (exact tanh form)
__device__ __forceinline__ float gelu_f(float x){
  float t = x * fmaf(0.0356774081f, x*x, 0.7978845608f);
  float u = __builtin_amdgcn_exp2f(-2.885390082f * t);
  return x * __builtin_amdgcn_rcpf(1.0f + u);
}

__device__ __forceinline__ void load16f(const __bf16* p, float* f){
  v8bf a = *(const v8bf*)p, b = *(const v8bf*)(p+8);
  #pragma unroll
  for (int i=0;i<8;i++){ f[i]=(float)a[i]; f[8+i]=(float)b[i]; }
}

// Weight fragments, issued early (prefetch), consumed after next barrier.
template<int KT,int NTPW> struct WF {
  v8bf  w[NTPW][KT];
  float4 b[NTPW];
};

// N-split loader: wave wv's NTPW consecutive N-tiles of one matrix.
template<int KT,int NTPW>
__device__ __forceinline__ WF<KT,NTPW> wload(const __bf16* __restrict__ Wt,
    const float* __restrict__ bias, int wv, int lane)
{
  WF<KT,NTPW> f;
  const int ar = lane&15, quad = lane>>4;
  #pragma unroll
  for (int ln=0; ln<NTPW; ln++){
    const int wt = wv*NTPW + ln;
    const __bf16* wp = Wt + (size_t)(wt*16+ar)*(KT*32) + quad*8;
    #pragma unroll
    for (int kt=0;kt<KT;kt++) f.w[ln][kt] = *(const v8bf*)(wp + kt*32);
    f.b[ln] = *(const float4*)(bias + wt*16 + quad*4);
  }
  return f;
}

// Fused-matrix loader: wave wv's N-tile (tile index wv) of NW matrices.
template<int KT,int NW>
__device__ __forceinline__ WF<KT,NW> wloadF(const __bf16* const* Ws,
    const float* const* bs, int wv, int lane)
{
  WF<KT,NW> f;
  const int ar = lane&15, quad = lane>>4;
  #pragma unroll
  for (int w=0; w<NW; w++){
    const __bf16* wp = Ws[w] + (size_t)(wv*16+ar)*(KT*32) + quad*8;
    #pragma unroll
    for (int kt=0;kt<KT;kt++) f.w[w][kt] = *(const v8bf*)(wp + kt*32);
    f.b[w] = *(const float4*)(bs[w] + wv*16 + quad*4);
  }
  return f;
}

// N-split GEMM, act-reuse order: one act read per (mt,kt) feeds all NTPW
// N-tile accumulators. Weights already in regs (prefetched).
template<int KT,int MT,int NTPW,typename LA,typename E>
__device__ __forceinline__ void gemmW(LA la, const WF<KT,NTPW>& f,
    int wv, int lane, E epi)
{
  const int ar = lane&15, quad = lane>>4;
  #pragma unroll
  for (int mt=0; mt<MT; mt++){
    v4f c[NTPW];
    #pragma unroll
    for (int ln=0;ln<NTPW;ln++){
      c[ln][0]=f.b[ln].x; c[ln][1]=f.b[ln].y; c[ln][2]=f.b[ln].z; c[ln][3]=f.b[ln].w;
    }
    #pragma unroll
    for (int kt=0;kt<KT;kt++){
      v8bf av = la(mt,kt,ar,quad);
      #pragma unroll
      for (int ln=0;ln<NTPW;ln++)
        c[ln] = __builtin_amdgcn_mfma_f32_16x16x32_bf16(f.w[ln][kt], av, c[ln], 0,0,0);
    }
    #pragma unroll
    for (int ln=0;ln<NTPW;ln++)
      epi((wv*NTPW+ln)*16 + quad*4, mt, ar, c[ln]);
  }
}

// Fused-matrix GEMM: one act read per (mt,kt) feeds NW matrices' tiles.
// epi(w, wb, mt, ar, c) — wb = wv*16+quad*4 within matrix w.
template<int KT,int MT,int NW,typename LA,typename E>
__device__ __forceinline__ void gemmF(LA la, const WF<KT,NW>& f,
    int wv, int lane, E epi)
{
  const int ar = lane&15, quad = lane>>4;
  #pragma unroll
  for (int mt=0; mt<MT; mt++){
    v4f c[NW];
    #pragma unroll
    for (int w=0;w<NW;w++){
      c[w][0]=f.b[w].x; c[w][1]=f.b[w].y; c[w][2]=f.b[w].z; c[w][3]=f.b[w].w;
    }
    #pragma unroll
    for (int kt=0;kt<KT;kt++){
      v8bf av = la(mt,kt,ar,quad);
      #pragma unroll
      for (int w=0;w<NW;w++)
        c[w] = __builtin_amdgcn_mfma_f32_16x16x32_bf16(f.w[w][kt], av, c[w], 0,0,0);
    }
    #pragma unroll
    for (int w=0;w<NW;w++)
      epi(w, wv*16 + quad*4, mt, ar, c[w]);
  }
}

// LDS map (bytes), total 53120 <= 53248 (proven 3 blocks/CU):
//  Ab   @0      bf16[64][136] 17408  (early: Df f32[12][32])
//  Bb   @17408  bf16[64][136] 17408  (early: TOKIN f32[60][12])
//  Tk   @34816  bf16[64][72]   9216  (early: OBSf f32[12][120]; late: Po bf16[12][64])
//  Pe   @44032  bf16[16][64]   2048
//  Eg   @46080  bf16[16][40]   1280
//  Ru   @47360  bf16[12][30]    736
//  mfb  @48096  bf16[64]        128
//  msfb @48224  bf16[64]        128
//  many @48352  f32[16]          64
//  lga  @48416  f32[64]         256
//  region @48672..53120 (4448 B), phase-overlaid:
//    S2-S3:  ATTb bf16[12][128] 3072 (padded [T][h][32])
//    S9-S11: ECX  bf16[16][64]  2048
//    S13-14: pattn f32[12][32]  1536 (padded [T][h][8])
//    S14-16: Cc   bf16[16][64]  2048 @50720
__global__ __launch_bounds__(256,3)
void swarm_mfma(P a, const __bf16* __restrict__ ws, int ntok)
{
  __shared__ char smem[53120] __attribute__((aligned(16)));
  __bf16* Ab   = (__bf16*)(smem);
  __bf16* Bb   = (__bf16*)(smem+17408);
  float*  TOKIN= (float*) (smem+17408);
  __bf16* Tk   = (__bf16*)(smem+34816);
  float*  OBSf = (float*) (smem+34816);
  __bf16* Po   = (__bf16*)(smem+34816);
  __bf16* Pe   = (__bf16*)(smem+44032);
  __bf16* Eg   = (__bf16*)(smem+46080);
  __bf16* Ru   = (__bf16*)(smem+47360);
  __bf16* mfb  = (__bf16*)(smem+48096);
  __bf16* msfb = (__bf16*)(smem+48224);
  float*  many = (float*) (smem+48352);
  float*  lga  = (float*) (smem+48416);
  __bf16* ECX  = (__bf16*)(smem+48672);
  __bf16* ATTb = (__bf16*)(smem+48672);   // [T][h][32] bf16, S2-S3 only
  float*  pattn= (float*) (smem+48672);   // [T][h][8] f32, S13-S14 only
  __bf16* Cc   = (__bf16*)(smem+50720);

  const int lane = threadIdx.x & 63;
  const int wv   = threadIdx.x >> 6;
  const int ar   = lane & 15, quad = lane >> 4;
  const long blkT0 = (long)blockIdx.x*12;

  // ================= setup (wave-local tokens 3wv..3wv+2) =================
  for (int it=lane; it<3*117; it+=64){
    int tg=it/117, c=it-tg*117;
    long gt = blkT0 + 3*wv + tg; if (gt>ntok-1) gt=ntok-1;
    OBSf[(3*wv+tg)*120+c] = a.obs[gt*DOBS+c];
  }
  float* Df = (float*)Ab;
  for (int it=lane; it<75; it+=64){
    int tg=it/25, p=it-tg*25, i=p/5, j=p-i*5;
    const float* ob = OBSf + (3*wv+tg)*120 + 32;
    float d2=0.f;
    #pragma unroll
    for (int d=0;d<3;d++){
      float ri=ob[15*i+d]; ri = isfinite(ri)?ri:0.f;
      float rj=ob[15*j+d]; rj = isfinite(rj)?rj:0.f;
      float df=ri-rj; d2 += df*df;
    }
    Df[(3*wv+tg)*32+p]=sqrtf(d2);
  }
  if (lane<15){
    int T=3*wv+lane/5, s=lane%5;
    const float* b = OBSf + T*120 + 32 + 15*s;
    mfb[15*wv+lane] = (__bf16)((fabsf(b[0])>1e-6f||fabsf(b[1])>1e-6f||fabsf(b[2])>1e-6f)?1.f:0.f);
  }
  if (wv==0 && lane>=60){ mfb[lane]=(__bf16)0.f; msfb[lane]=(__bf16)0.f; }
  if (wv==0 && lane>=12 && lane<16) many[lane]=0.f;
  if (lane<3){
    int T=3*wv+lane;
    float any = (float)mfb[T*5]+(float)mfb[T*5+1]+(float)mfb[T*5+2]+(float)mfb[T*5+3]+(float)mfb[T*5+4];
    float anyf = (any>0.f)?1.f:0.f; many[T]=anyf;
    #pragma unroll
    for (int i=0;i<5;i++) msfb[T*5+i] = (anyf>0.f)? mfb[T*5+i] : (__bf16)((i==0)?1.f:0.f);
  }
  if (lane<15){
    int T=3*wv+lane/5, i=lane%5, R=15*wv+lane;
    float dmin=1e9f,dsum=0.f,cnt=0.f;
    #pragma unroll
    for (int j=0;j<5;j++){
      if (j!=i && (float)mfb[T*5+i]>0.5f && (float)mfb[T*5+j]>0.5f){
        float dd=Df[T*32+i*5+j];
        dmin=fminf(dmin,dd); dsum+=dd; cnt+=1.f;
      }
    }
    TOKIN[R*12+10]=dmin;
    TOKIN[R*12+11]=(cnt>0.f)? dsum/(cnt+1e-9f) : 0.f;
  }
  for (int it=lane; it<150; it+=64){
    int tg=it/50, q=it-tg*50, s=q/10, c=q-s*10;
    int T=3*wv+tg;
    const float* b = OBSf + T*120 + 32 + 15*s;
    float v;
    if (c<4)        v=b[11+c];
    else if (c==4)  v=b[9];
    else if (c==5)  v=b[10];
    else if (c<9)   v=b[6+(c-6)];
    else { float a0=b[6],a1=b[7],a2=b[8]; v=sqrtf(a0*a0+a1*a1+a2*a2); }
    TOKIN[(T*5+s)*12+c]=v;
  }
  for (int it=lane; it<96; it+=64){
    int tg=it>>5, c=it&31;
    Eg[(3*wv+tg)*40+c] = (__bf16)OBSf[(3*wv+tg)*120+c];
  }
  for (int it=lane; it<90; it+=64){
    int tg=it/30, c=it-tg*30;
    Ru[(3*wv+tg)*30+c] = (__bf16)OBSf[(3*wv+tg)*120+32+15*(c/6)+(c%6)];
  }
  for (int it=lane; it<192; it+=64){
    int tg=it>>6, c=it&63;
    float acc = a.pr_b[c];
    #pragma unroll
    for (int k=0;k<10;k++) acc += OBSf[(3*wv+tg)*120+107+k]*a.pr_w[k*64+c];
    Pe[(3*wv+tg)*64+c] = (__bf16)gelu_f(acc);
  }
  BAR();   // S0: OBSf/Df/TOKIN producers done; Tk writes may begin

  // prefetch QKV weights (fused: 3 matrices, this wave's N-tile of each);
  // loads overlap tok-embed + ln1 and cross S1.
  const __bf16* WsQKV[3] = {ws+W_A1K, ws+W_A1V, ws+W_A1Q};
  const float*  bsQKV[3] = {a.a1_kb, a.a1_vb, a.a1_qb};
  auto wfQKV = wloadF<2,3>(WsQKV, bsQKV, wv, lane);

  // ---- P3: tok embed (fp32 K=12) -> Tk rows 15wv..15wv+14; then ln1 -> Ab ----
  {
    float w0[12];
    #pragma unroll
    for (int k=0;k<12;k++) w0[k] = a.tok_w[k*64+lane];
    float tb = a.tok_b[lane];
    for (int r=0;r<15;r++){
      int R = 15*wv + r;
      const float4* tin = (const float4*)(TOKIN + R*12);
      float4 x0 = tin[0], x1 = tin[1], x2 = tin[2];
      float acc = tb;
      acc=fmaf(x0.x,w0[0],acc); acc=fmaf(x0.y,w0[1],acc);
      acc=fmaf(x0.z,w0[2],acc); acc=fmaf(x0.w,w0[3],acc);
      acc=fmaf(x1.x,w0[4],acc); acc=fmaf(x1.y,w0[5],acc);
      acc=fmaf(x1.z,w0[6],acc); acc=fmaf(x1.w,w0[7],acc);
      acc=fmaf(x2.x,w0[8],acc); acc=fmaf(x2.y,w0[9],acc);
      acc=fmaf(x2.z,w0[10],acc); acc=fmaf(x2.w,w0[11],acc);
      Tk[R*72+lane] = (__bf16)(gelu_f(acc)*(float)mfb[R]);
    }
  }
  if (ar<15){   // ln1, own rows (shuffles stay within same-ar groups)
    int R = 15*wv + ar;
    float x[16]; load16f(Tk + R*72 + quad*16, x);
    float s=0.f;
    #pragma unroll
    for (int i=0;i<16;i++) s += x[i];
    s += __shfl_xor(s,16,64); s += __shfl_xor(s,32,64);
    float m = s*(1.f/64.f), q=0.f;
    #pragma unroll
    for (int i=0;i<16;i++){ float d=x[i]-m; q=fmaf(d,d,q); }
    q += __shfl_xor(q,16,64); q += __shfl_xor(q,32,64);
    float rs = __builtin_amdgcn_rsqf(q*(1.f/64.f)+1e-6f);
    v8bf o0,o1;
    #pragma unroll
    for (int i=0;i<8;i++){
      o0[i]=(__bf16)((x[i]  -m)*rs*a.ln1_s[quad*16+i]  +a.ln1_b[quad*16+i]);
      o1[i]=(__bf16)((x[8+i]-m)*rs*a.ln1_s[quad*16+8+i]+a.ln1_b[quad*16+8+i]);
    }
    *(v8bf*)(Ab+R*136+quad*16)=o0; *(v8bf*)(Ab+R*136+quad*16+8)=o1;
  }
  BAR();   // S1

  auto actAb = [&](int mt,int kt,int r,int q){ return *(const v8bf*)(Ab + (size_t)(mt*16+r)*136 + q*8 + kt*32); };
  auto actBb = [&](int mt,int kt,int r,int q){ return *(const v8bf*)(Bb + (size_t)(mt*16+r)*136 + q*8 + kt*32); };
  auto actTk = [&](int mt,int kt,int r,int q){ return *(const v8bf*)(Tk + (size_t)(mt*16+r)*72  + q*8 + kt*32); };

  // ---- QKV fused (one act read feeds K,V,Q): K -> Bb[:,64:], V -> Ab[:,64:],
  //      Q -> Bb[:,0:64] ----
  gemmF<2,4,3>(actAb, wfQKV, wv, lane,
    [&](int w,int wb,int mt,int r,v4f c){ v4bf o;
      #pragma unroll
      for (int k=0;k<4;k++) o[k]=(__bf16)c[k];
      __bf16* d = (w==0)? &Bb[(mt*16+r)*136+64+wb]
               : (w==1)? &Ab[(mt*16+r)*136+64+wb]
                       : &Bb[(mt*16+r)*136+wb];
      *(v4bf*)d = o; });
  auto wfO = wload<2,1>(ws+W_A1O, a.a1_ob, wv, lane);   // survives S2+S3
  BAR();   // S2

  // ---- attn weights + attn@V (wave-local tokens) ----
  if (lane<60){
    int tg=lane/20, rem=lane-tg*20, h=rem/5, i=rem-h*5;
    int T=3*wv+tg;
    bool mi = (float)msfb[T*5+i]>0.5f;
    float qv[16]; load16f(&Bb[(T*5+i)*136 + h*16], qv);
    float lgv[5], mx=NEG_INF_F;
    #pragma unroll
    for (int j=0;j<5;j++){
      float kk[16]; load16f(&Bb[(T*5+j)*136 + 64 + h*16], kk);
      float d=0.f;
      #pragma unroll
      for (int dd=0;dd<16;dd++) d += qv[dd]*kk[dd];
      bool mj = (float)msfb[T*5+j]>0.5f;
      lgv[j] = (mi&&mj)? d*0.25f : NEG_INF_F;
      mx = fmaxf(mx,lgv[j]);
    }
    float sum=0.f, ex[5];
    #pragma unroll
    for (int j=0;j<5;j++){ ex[j]=__expf(lgv[j]-mx); sum+=ex[j]; }
    float inv=1.0f/sum;
    #pragma unroll
    for (int j=0;j<5;j++) ATTb[T*128 + h*32 + i*5+j]=(__bf16)(ex[j]*inv);
  }
  {
    int h = lane>>4;
    #pragma unroll
    for (int tg=0; tg<3; tg++){
      int T=3*wv+tg;
      float v5[5];
      #pragma unroll
      for (int j=0;j<5;j++) v5[j] = (float)Ab[(T*5+j)*136+64+lane];
      const __bf16* wp = ATTb + T*128 + h*32;
      v8bf w0 = *(const v8bf*)(wp);
      v8bf w1 = *(const v8bf*)(wp+8);
      v8bf w2 = *(const v8bf*)(wp+16);
      v8bf w3 = *(const v8bf*)(wp+24);
      float wf[32];
      #pragma unroll
      for (int k=0;k<8;k++){
        wf[k]=(float)w0[k]; wf[8+k]=(float)w1[k];
        wf[16+k]=(float)w2[k]; wf[24+k]=(float)w3[k];
      }
      #pragma unroll
      for (int i=0;i<5;i++){
        float o=0.f;
        #pragma unroll
        for (int j=0;j<5;j++) o += wf[i*5+j]*v5[j];
        Ab[(T*5+i)*136+lane]=(__bf16)o;
      }
    }
  }
  BAR();   // S3

  // ---- o-proj + residual -> Tk (col-slices) ----
  gemmW<2,4,1>(actAb, wfO, wv, lane,
    [&](int wb,int mt,int r,v4f c){
      int R=mt*16+r; float mm=(float)mfb[R];
      v4bf old=*(const v4bf*)&Tk[R*72+wb]; v4bf o;
      #pragma unroll
      for (int k=0;k<4;k++) o[k]=(__bf16)((float)old[k]+c[k]*mm);
      *(v4bf*)&Tk[R*72+wb]=o; });
  auto wfM1 = wload<2,2>(ws+W_M1, a.m1_b, wv, lane);    // survives S4+S5
  BAR();   // S4

  // ---- ln2 -> Ab[:,0:64] (own rows) ----
  if (ar<15){
    int R = 15*wv + ar;
    float x[16]; load16f(Tk + R*72 + quad*16, x);
    float s=0.f;
    #pragma unroll
    for (int i=0;i<16;i++) s += x[i];
    s += __shfl_xor(s,16,64); s += __shfl_xor(s,32,64);
    float m = s*(1.f/64.f), q=0.f;
    #pragma unroll
    for (int i=0;i<16;i++){ float d=x[i]-m; q=fmaf(d,d,q); }
    q += __shfl_xor(q,16,64); q += __shfl_xor(q,32,64);
    float rs = __builtin_amdgcn_rsqf(q*(1.f/64.f)+1e-6f);
    v8bf o0,o1;
    #pragma unroll
    for (int i=0;i<8;i++){
      o0[i]=(__bf16)((x[i]  -m)*rs*a.ln2_s[quad*16+i]  +a.ln2_b[quad*16+i]);
      o1[i]=(__bf16)((x[8+i]-m)*rs*a.ln2_s[quad*16+8+i]+a.ln2_b[quad*16+8+i]);
    }
    *(v8bf*)(Ab+R*136+quad*16)=o0; *(v8bf*)(Ab+R*136+quad*16+8)=o1;
  }
  BAR();   // S5

  // ---- m1 -> Bb[:,0:128] ----
  gemmW<2,4,2>(actAb, wfM1, wv, lane,
    [&](int wb,int mt,int r,v4f c){ v4bf o;
      #pragma unroll
      for (int k=0;k<4;k++) o[k]=(__bf16)gelu_f(c[k]);
      *(v4bf*)&Bb[(mt*16+r)*136+wb]=o; });
  auto wfM2 = wload<4,2>(ws+W_M2, a.m2_b, wv, lane);
  BAR();   // S6
  // ---- m2 -> Ab[:,0:128] ----
  gemmW<4,4,2>(actBb, wfM2, wv, lane,
    [&](int wb,int mt,int r,v4f c){ v4bf o;
      #pragma unroll
      for (int k=0;k<4;k++) o[k]=(__bf16)gelu_f(c[k]);
      *(v4bf*)&Ab[(mt*16+r)*136+wb]=o; });
  auto wfM3 = wload<4,1>(ws+W_M3, a.m3_b, wv, lane);
  auto wfE1 = wload<1,2>(ws+W_E1, a.e1_b, wv, lane);
  BAR();   // S7
  // ---- m3 -> Tk (resid*mask) ; e1 (token-level) -> Bb rows 0..15 ----
  gemmW<4,4,1>(actAb, wfM3, wv, lane,
    [&](int wb,int mt,int r,v4f c){
      int R=mt*16+r; float mm=(float)mfb[R];
      v4bf old=*(const v4bf*)&Tk[R*72+wb]; v4bf o;
      #pragma unroll
      for (int k=0;k<4;k++) o[k]=(__bf16)(((float)old[k]+c[k]*mm)*mm);
      *(v4bf*)&Tk[R*72+wb]=o; });
  gemmW<1,1,2>([&](int,int,int r,int q){ return *(const v8bf*)(Eg + (size_t)r*40 + q*8); },
    wfE1, wv, lane,
    [&](int wb,int mt,int r,v4f c){ v4bf o;
      #pragma unroll
      for (int k=0;k<4;k++) o[k]=(__bf16)gelu_f(c[k]);
      *(v4bf*)&Bb[r*136+wb]=o; });
  auto wfE2 = wload<4,2>(ws+W_E2, a.e2_b, wv, lane);
  BAR();   // S8
  // ---- e2 -> Ab rows 0..15 ----
  gemmW<4,1,2>(actBb, wfE2, wv, lane,
    [&](int wb,int mt,int r,v4f c){ v4bf o;
      #pragma unroll
      for (int k=0;k<4;k++) o[k]=(__bf16)gelu_f(c[k]);
      *(v4bf*)&Ab[r*136+wb]=o; });
  auto wfE3 = wload<4,1>(ws+W_E3, a.e3_b, wv, lane);
  BAR();   // S9
  // ---- e3 -> ECX rows 0..15 ----
  gemmW<4,1,1>(actAb, wfE3, wv, lane,
    [&](int wb,int mt,int r,v4f c){ v4bf o;
      #pragma unroll
      for (int k=0;k<4;k++) o[k]=(__bf16)c[k];
      *(v4bf*)&ECX[r*64+wb]=o; });
  auto wfL1 = wload<4,2>(ws+W_L1, a.l1_b, wv, lane);
  BAR();   // S10
  // ---- l1 (act = [Tk | ECX(token)]) -> Bb[:,0:128] ----
  gemmW<4,4,2>([&](int mt,int kt,int r,int q){
      int R=mt*16+r;
      return (kt<2) ? *(const v8bf*)(Tk + (size_t)R*72 + q*8 + kt*32)
                    : *(const v8bf*)(ECX + (size_t)((R*205)>>10)*64 + q*8 + (kt-2)*32); },
    wfL1, wv, lane,
    [&](int wb,int mt,int r,v4f c){ v4bf o;
      #pragma unroll
      for (int k=0;k<4;k++) o[k]=(__bf16)gelu_f(c[k]);
      *(v4bf*)&Bb[(mt*16+r)*136+wb]=o; });
  auto wfL2 = wload<4,2>(ws+W_L2, a.l2_b, wv, lane);
  BAR();   // S11
  // ---- l2 -> Ab[:,0:128] ----
  gemmW<4,4,2>(actBb, wfL2, wv, lane,
    [&](int wb,int mt,int r,v4f c){ v4bf o;
      #pragma unroll
      for (int k=0;k<4;k++) o[k]=(__bf16)gelu_f(c[k]);
      *(v4bf*)&Ab[(mt*16+r)*136+wb]=o; });
  const __bf16* WsPKV[2] = {ws+W_PK, ws+W_PV};
  const float*  bsPKV[2] = {a.p_kb, a.p_vb};
  auto wfPKV = wloadF<2,2>(WsPKV, bsPKV, wv, lane);
  BAR();   // S12

  // ---- l3 (own rows) + alpha + v_r/v_u ; kp/vp fused -> Bb ----
  if (ar<15){
    int R = 15*wv + ar;
    float x[16], y[16];
    load16f(&Ab[R*136 + quad*32], x);
    load16f(&Ab[R*136 + quad*32 + 16], y);
    const float* w = a.l3_w + quad*32;
    float p = 0.f;
    #pragma unroll
    for (int i=0;i<16;i++) p = fmaf(x[i], w[i], p);
    #pragma unroll
    for (int i=0;i<16;i++) p = fmaf(y[i], w[16+i], p);
    p += __shfl_xor(p,16,64); p += __shfl_xor(p,32,64);
    if (quad==0) lga[R] = p + a.l3_b[0];
  }
  gemmF<2,4,2>(actTk, wfPKV, wv, lane,
    [&](int w,int wb,int mt,int r,v4f c){ v4bf o;
      #pragma unroll
      for (int k=0;k<4;k++) o[k]=(__bf16)c[k];
      *(v4bf*)&Bb[(mt*16+r)*136 + (w?64:0) + wb] = o; });
  if (lane<3){
    int T=3*wv+lane;
    float ml[5], mx=-1e9f;
    #pragma unroll
    for (int i=0;i<5;i++){ ml[i]=((float)mfb[T*5+i]>0.5f)? lga[T*5+i] : -1e9f; mx=fmaxf(mx,ml[i]); }
    float den=0.f, e[5];
    #pragma unroll
    for (int i=0;i<5;i++){ e[i]=__expf(ml[i]-mx)*(float)mfb[T*5+i]; den+=e[i]; }
    float inv=1.0f/(den+1e-9f);
    #pragma unroll
    for (int i=0;i<5;i++) lga[T*5+i]=e[i]*inv;
  }
  if (lane<18){
    int tg=lane/6, c=lane-tg*6;
    int T=3*wv+tg;
    float v=0.f;
    #pragma unroll
    for (int i=0;i<5;i++) v += lga[T*5+i]*(float)Ru[T*30+i*6+c];
    long tk = blkT0 + T;
    if (tk<ntok) a.out[tk*134+128+c]=v;
  }
  BAR();   // S13

  // ---- pooling attn + pooled-o (wave-local tokens) ----
  if (lane<12){
    const float* qg = (const float*)(ws + W_QP);
    int tg=lane>>2, h=lane&3;
    int T=3*wv+tg;
    float qv[16];
    #pragma unroll
    for (int dd=0;dd<16;dd++) qv[dd]=qg[h*16+dd];
    float lgv[5], mx=NEG_INF_F;
    #pragma unroll
    for (int j=0;j<5;j++){
      float kk[16]; load16f(&Bb[(T*5+j)*136 + h*16], kk);
      float d=0.f;
      #pragma unroll
      for (int dd=0;dd<16;dd++) d += qv[dd]*kk[dd];
      lgv[j] = ((float)msfb[T*5+j]>0.5f)? d*0.25f : NEG_INF_F;
      mx = fmaxf(mx,lgv[j]);
    }
    float sum=0.f, ex[5];
    #pragma unroll
    for (int j=0;j<5;j++){ ex[j]=__expf(lgv[j]-mx); sum+=ex[j]; }
    float inv=1.0f/sum;
    #pragma unroll
    for (int j=0;j<5;j++) pattn[T*32+h*8+j]=ex[j]*inv;
  }
  for (int it=lane; it<192; it+=64){
    int tg=it>>6, c=it&63, h=c>>4;
    int T=3*wv+tg;
    const float* pp2 = pattn + T*32 + h*8;
    float4 p4 = *(const float4*)pp2;
    float p4v = pp2[4];
    float o=0.f;
    o += p4.x*(float)Bb[(T*5+0)*136+64+c];
    o += p4.y*(float)Bb[(T*5+1)*136+64+c];
    o += p4.z*(float)Bb[(T*5+2)*136+64+c];
    o += p4.w*(float)Bb[(T*5+3)*136+64+c];
    o += p4v *(float)Bb[(T*5+4)*136+64+c];
    Po[T*64+c]=(__bf16)o;
  }
  auto wfPO = wload<2,1>(ws+W_PO, a.p_ob, wv, lane);
  BAR();   // S14

  // ---- p_ow -> Cc (x many) ----
  gemmW<2,1,1>([&](int,int kt,int r,int q){ return *(const v8bf*)(Po + (size_t)r*64 + q*8 + kt*32); },
    wfPO, wv, lane,
    [&](int wb,int mt,int r,v4f c){
      float mm = many[r];
      v4bf o;
      #pragma unroll
      for (int k=0;k<4;k++) o[k]=(__bf16)(c[k]*mm);
      *(v4bf*)&Cc[r*64+wb]=o; });
  auto wfH1 = wload<5,2>(ws+W_H1, a.h1_b, wv, lane);
  BAR();   // S15

  // ---- h1 (act = [Eg | Cc | Pe], K=160) -> Bb rows 0..15 ----
  gemmW<5,1,2>([&](int,int kt,int r,int q){
      if (kt==0) return *(const v8bf*)(Eg + (size_t)r*40 + q*8);
      if (kt<3)  return *(const v8bf*)(Cc + (size_t)r*64 + q*8 + (kt-1)*32);
      return *(const v8bf*)(Pe + (size_t)r*64 + q*8 + (kt-3)*32); },
    wfH1, wv, lane,
    [&](int wb,int mt,int r,v4f c){ v4bf o;
      #pragma unroll
      for (int k=0;k<4;k++) o[k]=(__bf16)gelu_f(c[k]);
      *(v4bf*)&Bb[r*136+wb]=o; });
  auto wfH2 = wload<4,2>(ws+W_H2, a.h2_b, wv, lane);
  BAR();   // S16
  // ---- h2 -> Ab rows 0..15 ----
  gemmW<4,1,2>(actBb, wfH2, wv, lane,
    [&](int wb,int mt,int r,v4f c){ v4bf o;
      #pragma unroll
      for (int k=0;k<4;k++) o[k]=(__bf16)gelu_f(c[k]);
      *(v4bf*)&Ab[r*136+wb]=o; });
  auto wfH3 = wload<4,2>(ws+W_H3, a.h3_b, wv, lane);
  BAR();   // S17
  // ---- h3 -> out ----
  gemmW<4,1,2>(actAb, wfH3, wv, lane,
    [&](int wb,int mt,int r,v4f c){
      long tk = blkT0 + r;
      if (r<12 && tk<ntok){
        float2* o2 = (float2*)&a.out[tk*134 + wb];
        o2[0] = make_float2(c[0], c[1]);
        o2[1] = make_float2(c[2], c[3]);
      } });
}

extern "C" void kernel_launch(void* const* d_in, const int* in_sizes, int n_in,
                              void* d_out, int out_size, void* d_ws, size_t ws_size,
                              hipStream_t stream)
{
  P a;
  const float** pp = reinterpret_cast<const float**>(&a);
  for (int i=0;i<50;i++) pp[i] = reinterpret_cast<const float*>(d_in[i]);
  a.out = reinterpret_cast<float*>(d_out);
  int ntok = in_sizes[0] / DOBS;   // 65536

  __bf16* ws = reinterpret_cast<__bf16*>(d_ws);
  hipLaunchKernelGGL(prep_w, dim3(173), dim3(256), 0, stream, a, ws);
  hipLaunchKernelGGL(swarm_mfma, dim3((ntok+11)/12), dim3(256), 0, stream, a, ws, ntok);
}

// Round 12
// 469.658 us; speedup vs baseline: 1.0643x; 1.0073x over previous
//
#include <hip/hip_runtime.h>
#include <math.h>

// SwarmSetEquivariantTorso — bf16 MFMA, N-split block GEMMs, 12 tok/block.
// HISTORY: R0 375us | R5 463us (weight-batch poison) | R7 437us (occupancy
// not lever) | R8 361us (WIN: weight prefetch across non-draining BAR)
// R9 363.6us (phase-fusion NEUTRAL) | R10 354us (WIN: act-read reuse)
// R11 339us (WIN: attn/pool LDS vectorization, padded ATTb/pattn).
// THIS = R11 + param-load hoisting (R8 family applied to glue params):
// BAR()'s "memory" clobber pins loads after barriers -> every post-barrier
// param load stalls phase entry on L2. Hoisted above preceding BAR:
//  tok_w/tok_b + ln1 s/b (pre-S0), ln2 s/b (pre-S4, with wfM1),
//  l3_w/l3_b (pre-S12, with wfPKV), pool query qg (pre-S13).
// All unrolled constant-indexed -> registers (no scratch).

#define DOBS 198
#define NEG_INF_F (-3.402823466e38f)

// Non-draining barrier: LDS visibility via lgkmcnt(0); global (weight)
// loads stay in flight. No cross-wave global communication in-kernel.
#define BAR() do { asm volatile("s_waitcnt lgkmcnt(0)" ::: "memory"); \
                   __builtin_amdgcn_s_barrier(); } while(0)

typedef __bf16 v8bf __attribute__((ext_vector_type(8)));
typedef __bf16 v4bf __attribute__((ext_vector_type(4)));
typedef float  v4f  __attribute__((ext_vector_type(4)));

struct P {
  const float *obs,*tok_w,*tok_b,*ln1_s,*ln1_b,
    *a1_qw,*a1_qb,*a1_kw,*a1_kb,*a1_vw,*a1_vb,*a1_ow,*a1_ob,
    *ln2_s,*ln2_b,*m1_w,*m1_b,*m2_w,*m2_b,*m3_w,*m3_b,
    *e1_w,*e1_b,*e2_w,*e2_b,*e3_w,*e3_b,
    *l1_w,*l1_b,*l2_w,*l2_b,*l3_w,*l3_b,
    *seed,*p_qw,*p_qb,*p_kw,*p_kb,*p_vw,*p_vb,*p_ow,*p_ob,
    *pr_w,*pr_b,*h1_w,*h1_b,*h2_w,*h2_b,*h3_w,*h3_b;
  float* out;
};
static_assert(sizeof(P) == 51*sizeof(void*), "P layout");

// ws bf16 weight image, W_t[n][k] per matrix (element offsets)
#define W_A1Q 0
#define W_A1K 4096
#define W_A1V 8192
#define W_A1O 12288
#define W_M1  16384
#define W_M2  24576
#define W_M3  40960
#define W_E1  49152
#define W_E2  53248
#define W_E3  69632
#define W_L1  77824
#define W_L2  94208
#define W_PK  110592
#define W_PV  114688
#define W_PO  118784
#define W_H1  122880
#define W_H2  143360
#define W_H3  159744
#define W_END 176128
#define W_QP  176128   // + 64 f32 (pooling query, precomputed)

__global__ __launch_bounds__(256)
void prep_w(P a, __bf16* ws)
{
  if (blockIdx.x == 172){
    int t = threadIdx.x;
    if (t < 64){
      float acc = a.p_qb[t];
      for (int k=0;k<64;k++) acc += a.seed[k]*a.p_qw[k*64+t];
      ((float*)(ws + W_QP))[t] = acc;
    }
    return;
  }
  const float* srcs[18] = {a.a1_qw,a.a1_kw,a.a1_vw,a.a1_ow,a.m1_w,a.m2_w,a.m3_w,
                           a.e1_w,a.e2_w,a.e3_w,a.l1_w,a.l2_w,a.p_kw,a.p_vw,a.p_ow,
                           a.h1_w,a.h2_w,a.h3_w};
  const int Ks[18]   = {64,64,64,64,64,128,128,32,128,128,128,128,64,64,64,160,128,128};
  const int Ns[18]   = {64,64,64,64,128,128,64,128,128,64,128,128,64,64,64,128,128,128};
  const int offs[18] = {W_A1Q,W_A1K,W_A1V,W_A1O,W_M1,W_M2,W_M3,W_E1,W_E2,W_E3,
                        W_L1,W_L2,W_PK,W_PV,W_PO,W_H1,W_H2,W_H3};
  __shared__ float tile[32][33];
  int b = blockIdx.x, m = 0, acc = 0;
  for (; m < 18; m++){
    int t = (Ks[m]/32)*(Ns[m]/32);
    if (b < acc + t) break;
    acc += t;
  }
  int lt = b - acc, K = Ks[m], N = Ns[m];
  int ntile = N/32, kt = lt/ntile, nt = lt%ntile;
  int tx = threadIdx.x & 31, ty = threadIdx.x >> 5;
  const float* S = srcs[m];
  #pragma unroll
  for (int rr=0; rr<32; rr+=8)
    tile[ty+rr][tx] = S[(size_t)(kt*32+ty+rr)*N + nt*32+tx];
  __syncthreads();
  __bf16* D = ws + offs[m];
  #pragma unroll
  for (int rr=0; rr<32; rr+=8)
    D[(size_t)(nt*32+ty+rr)*K + kt*32+tx] = (__bf16)tile[tx][ty+rr];
}

// gelu(x) = x * sigmoid(2t),  t = 0.79788456(x + 0.044715 x^3)  (exact tanh form)
__device__ __forceinline__ float gelu_f(float x){
  float t = x * fmaf(0.0356774081f, x*x, 0.7978845608f);
  float u = __builtin_amdgcn_exp2f(-2.885390082f * t);
  return x * __builtin_amdgcn_rcpf(1.0f + u);
}

__device__ __forceinline__ void load16f(const __bf16* p, float* f){
  v8bf a = *(const v8bf*)p, b = *(const v8bf*)(p+8);
  #pragma unroll
  for (int i=0;i<8;i++){ f[i]=(float)a[i]; f[8+i]=(float)b[i]; }
}

// 16 f32 params as 4x float4 into constant-indexed regs.
__device__ __forceinline__ void load16p(const float* p, float* f){
  #pragma unroll
  for (int i=0;i<4;i++){
    float4 v = *(const float4*)(p + i*4);
    f[i*4+0]=v.x; f[i*4+1]=v.y; f[i*4+2]=v.z; f[i*4+3]=v.w;
  }
}

// Weight fragments, issued early (prefetch), consumed after next barrier.
template<int KT,int NTPW> struct WF {
  v8bf  w[NTPW][KT];
  float4 b[NTPW];
};

// N-split loader: wave wv's NTPW consecutive N-tiles of one matrix.
template<int KT,int NTPW>
__device__ __forceinline__ WF<KT,NTPW> wload(const __bf16* __restrict__ Wt,
    const float* __restrict__ bias, int wv, int lane)
{
  WF<KT,NTPW> f;
  const int ar = lane&15, quad = lane>>4;
  #pragma unroll
  for (int ln=0; ln<NTPW; ln++){
    const int wt = wv*NTPW + ln;
    const __bf16* wp = Wt + (size_t)(wt*16+ar)*(KT*32) + quad*8;
    #pragma unroll
    for (int kt=0;kt<KT;kt++) f.w[ln][kt] = *(const v8bf*)(wp + kt*32);
    f.b[ln] = *(const float4*)(bias + wt*16 + quad*4);
  }
  return f;
}

// Fused-matrix loader: wave wv's N-tile (tile index wv) of NW matrices.
template<int KT,int NW>
__device__ __forceinline__ WF<KT,NW> wloadF(const __bf16* const* Ws,
    const float* const* bs, int wv, int lane)
{
  WF<KT,NW> f;
  const int ar = lane&15, quad = lane>>4;
  #pragma unroll
  for (int w=0; w<NW; w++){
    const __bf16* wp = Ws[w] + (size_t)(wv*16+ar)*(KT*32) + quad*8;
    #pragma unroll
    for (int kt=0;kt<KT;kt++) f.w[w][kt] = *(const v8bf*)(wp + kt*32);
    f.b[w] = *(const float4*)(bs[w] + wv*16 + quad*4);
  }
  return f;
}

// N-split GEMM, act-reuse order: one act read per (mt,kt) feeds all NTPW
// N-tile accumulators. Weights already in regs (prefetched).
template<int KT,int MT,int NTPW,typename LA,typename E>
__device__ __forceinline__ void gemmW(LA la, const WF<KT,NTPW>& f,
    int wv, int lane, E epi)
{
  const int ar = lane&15, quad = lane>>4;
  #pragma unroll
  for (int mt=0; mt<MT; mt++){
    v4f c[NTPW];
    #pragma unroll
    for (int ln=0;ln<NTPW;ln++){
      c[ln][0]=f.b[ln].x; c[ln][1]=f.b[ln].y; c[ln][2]=f.b[ln].z; c[ln][3]=f.b[ln].w;
    }
    #pragma unroll
    for (int kt=0;kt<KT;kt++){
      v8bf av = la(mt,kt,ar,quad);
      #pragma unroll
      for (int ln=0;ln<NTPW;ln++)
        c[ln] = __builtin_amdgcn_mfma_f32_16x16x32_bf16(f.w[ln][kt], av, c[ln], 0,0,0);
    }
    #pragma unroll
    for (int ln=0;ln<NTPW;ln++)
      epi((wv*NTPW+ln)*16 + quad*4, mt, ar, c[ln]);
  }
}

// Fused-matrix GEMM: one act read per (mt,kt) feeds NW matrices' tiles.
// epi(w, wb, mt, ar, c) — wb = wv*16+quad*4 within matrix w.
template<int KT,int MT,int NW,typename LA,typename E>
__device__ __forceinline__ void gemmF(LA la, const WF<KT,NW>& f,
    int wv, int lane, E epi)
{
  const int ar = lane&15, quad = lane>>4;
  #pragma unroll
  for (int mt=0; mt<MT; mt++){
    v4f c[NW];
    #pragma unroll
    for (int w=0;w<NW;w++){
      c[w][0]=f.b[w].x; c[w][1]=f.b[w].y; c[w][2]=f.b[w].z; c[w][3]=f.b[w].w;
    }
    #pragma unroll
    for (int kt=0;kt<KT;kt++){
      v8bf av = la(mt,kt,ar,quad);
      #pragma unroll
      for (int w=0;w<NW;w++)
        c[w] = __builtin_amdgcn_mfma_f32_16x16x32_bf16(f.w[w][kt], av, c[w], 0,0,0);
    }
    #pragma unroll
    for (int w=0;w<NW;w++)
      epi(w, wv*16 + quad*4, mt, ar, c[w]);
  }
}

// LDS map (bytes), total 53120 <= 53248 (proven 3 blocks/CU):
//  Ab   @0      bf16[64][136] 17408  (early: Df f32[12][32])
//  Bb   @17408  bf16[64][136] 17408  (early: TOKIN f32[60][12])
//  Tk   @34816  bf16[64][72]   9216  (early: OBSf f32[12][120]; late: Po bf16[12][64])
//  Pe   @44032  bf16[16][64]   2048
//  Eg   @46080  bf16[16][40]   1280
//  Ru   @47360  bf16[12][30]    736
//  mfb  @48096  bf16[64]        128
//  msfb @48224  bf16[64]        128
//  many @48352  f32[16]          64
//  lga  @48416  f32[64]         256
//  region @48672..53120 (4448 B), phase-overlaid:
//    S2-S3:  ATTb bf16[12][128] 3072 (padded [T][h][32])
//    S9-S11: ECX  bf16[16][64]  2048
//    S13-14: pattn f32[12][32]  1536 (padded [T][h][8])
//    S14-16: Cc   bf16[16][64]  2048 @50720
__global__ __launch_bounds__(256,3)
void swarm_mfma(P a, const __bf16* __restrict__ ws, int ntok)
{
  __shared__ char smem[53120] __attribute__((aligned(16)));
  __bf16* Ab   = (__bf16*)(smem);
  __bf16* Bb   = (__bf16*)(smem+17408);
  float*  TOKIN= (float*) (smem+17408);
  __bf16* Tk   = (__bf16*)(smem+34816);
  float*  OBSf = (float*) (smem+34816);
  __bf16* Po   = (__bf16*)(smem+34816);
  __bf16* Pe   = (__bf16*)(smem+44032);
  __bf16* Eg   = (__bf16*)(smem+46080);
  __bf16* Ru   = (__bf16*)(smem+47360);
  __bf16* mfb  = (__bf16*)(smem+48096);
  __bf16* msfb = (__bf16*)(smem+48224);
  float*  many = (float*) (smem+48352);
  float*  lga  = (float*) (smem+48416);
  __bf16* ECX  = (__bf16*)(smem+48672);
  __bf16* ATTb = (__bf16*)(smem+48672);   // [T][h][32] bf16, S2-S3 only
  float*  pattn= (float*) (smem+48672);   // [T][h][8] f32, S13-S14 only
  __bf16* Cc   = (__bf16*)(smem+50720);

  const int lane = threadIdx.x & 63;
  const int wv   = threadIdx.x >> 6;
  const int ar   = lane & 15, quad = lane >> 4;
  const long blkT0 = (long)blockIdx.x*12;

  // ================= setup (wave-local tokens 3wv..3wv+2) =================
  for (int it=lane; it<3*117; it+=64){
    int tg=it/117, c=it-tg*117;
    long gt = blkT0 + 3*wv + tg; if (gt>ntok-1) gt=ntok-1;
    OBSf[(3*wv+tg)*120+c] = a.obs[gt*DOBS+c];
  }
  float* Df = (float*)Ab;
  for (int it=lane; it<75; it+=64){
    int tg=it/25, p=it-tg*25, i=p/5, j=p-i*5;
    const float* ob = OBSf + (3*wv+tg)*120 + 32;
    float d2=0.f;
    #pragma unroll
    for (int d=0;d<3;d++){
      float ri=ob[15*i+d]; ri = isfinite(ri)?ri:0.f;
      float rj=ob[15*j+d]; rj = isfinite(rj)?rj:0.f;
      float df=ri-rj; d2 += df*df;
    }
    Df[(3*wv+tg)*32+p]=sqrtf(d2);
  }
  if (lane<15){
    int T=3*wv+lane/5, s=lane%5;
    const float* b = OBSf + T*120 + 32 + 15*s;
    mfb[15*wv+lane] = (__bf16)((fabsf(b[0])>1e-6f||fabsf(b[1])>1e-6f||fabsf(b[2])>1e-6f)?1.f:0.f);
  }
  if (wv==0 && lane>=60){ mfb[lane]=(__bf16)0.f; msfb[lane]=(__bf16)0.f; }
  if (wv==0 && lane>=12 && lane<16) many[lane]=0.f;
  if (lane<3){
    int T=3*wv+lane;
    float any = (float)mfb[T*5]+(float)mfb[T*5+1]+(float)mfb[T*5+2]+(float)mfb[T*5+3]+(float)mfb[T*5+4];
    float anyf = (any>0.f)?1.f:0.f; many[T]=anyf;
    #pragma unroll
    for (int i=0;i<5;i++) msfb[T*5+i] = (anyf>0.f)? mfb[T*5+i] : (__bf16)((i==0)?1.f:0.f);
  }
  if (lane<15){
    int T=3*wv+lane/5, i=lane%5, R=15*wv+lane;
    float dmin=1e9f,dsum=0.f,cnt=0.f;
    #pragma unroll
    for (int j=0;j<5;j++){
      if (j!=i && (float)mfb[T*5+i]>0.5f && (float)mfb[T*5+j]>0.5f){
        float dd=Df[T*32+i*5+j];
        dmin=fminf(dmin,dd); dsum+=dd; cnt+=1.f;
      }
    }
    TOKIN[R*12+10]=dmin;
    TOKIN[R*12+11]=(cnt>0.f)? dsum/(cnt+1e-9f) : 0.f;
  }
  for (int it=lane; it<150; it+=64){
    int tg=it/50, q=it-tg*50, s=q/10, c=q-s*10;
    int T=3*wv+tg;
    const float* b = OBSf + T*120 + 32 + 15*s;
    float v;
    if (c<4)        v=b[11+c];
    else if (c==4)  v=b[9];
    else if (c==5)  v=b[10];
    else if (c<9)   v=b[6+(c-6)];
    else { float a0=b[6],a1=b[7],a2=b[8]; v=sqrtf(a0*a0+a1*a1+a2*a2); }
    TOKIN[(T*5+s)*12+c]=v;
  }
  for (int it=lane; it<96; it+=64){
    int tg=it>>5, c=it&31;
    Eg[(3*wv+tg)*40+c] = (__bf16)OBSf[(3*wv+tg)*120+c];
  }
  for (int it=lane; it<90; it+=64){
    int tg=it/30, c=it-tg*30;
    Ru[(3*wv+tg)*30+c] = (__bf16)OBSf[(3*wv+tg)*120+32+15*(c/6)+(c%6)];
  }
  for (int it=lane; it<192; it+=64){
    int tg=it>>6, c=it&63;
    float acc = a.pr_b[c];
    #pragma unroll
    for (int k=0;k<10;k++) acc += OBSf[(3*wv+tg)*120+107+k]*a.pr_w[k*64+c];
    Pe[(3*wv+tg)*64+c] = (__bf16)gelu_f(acc);
  }
  // hoisted params (R8 family): loads cross S0, consumed in tok-embed/ln1
  float w0[12];
  #pragma unroll
  for (int k=0;k<12;k++) w0[k] = a.tok_w[k*64+lane];
  float tb = a.tok_b[lane];
  float s1f[16], b1f[16];
  load16p(a.ln1_s + quad*16, s1f);
  load16p(a.ln1_b + quad*16, b1f);
  BAR();   // S0: OBSf/Df/TOKIN producers done; Tk writes may begin

  // prefetch QKV weights (fused: 3 matrices, this wave's N-tile of each);
  // loads overlap tok-embed + ln1 and cross S1.
  const __bf16* WsQKV[3] = {ws+W_A1K, ws+W_A1V, ws+W_A1Q};
  const float*  bsQKV[3] = {a.a1_kb, a.a1_vb, a.a1_qb};
  auto wfQKV = wloadF<2,3>(WsQKV, bsQKV, wv, lane);

  // ---- P3: tok embed (fp32 K=12) -> Tk rows 15wv..15wv+14; then ln1 -> Ab ----
  {
    for (int r=0;r<15;r++){
      int R = 15*wv + r;
      const float4* tin = (const float4*)(TOKIN + R*12);
      float4 x0 = tin[0], x1 = tin[1], x2 = tin[2];
      float acc = tb;
      acc=fmaf(x0.x,w0[0],acc); acc=fmaf(x0.y,w0[1],acc);
      acc=fmaf(x0.z,w0[2],acc); acc=fmaf(x0.w,w0[3],acc);
      acc=fmaf(x1.x,w0[4],acc); acc=fmaf(x1.y,w0[5],acc);
      acc=fmaf(x1.z,w0[6],acc); acc=fmaf(x1.w,w0[7],acc);
      acc=fmaf(x2.x,w0[8],acc); acc=fmaf(x2.y,w0[9],acc);
      acc=fmaf(x2.z,w0[10],acc); acc=fmaf(x2.w,w0[11],acc);
      Tk[R*72+lane] = (__bf16)(gelu_f(acc)*(float)mfb[R]);
    }
  }
  if (ar<15){   // ln1, own rows (shuffles stay within same-ar groups)
    int R = 15*wv + ar;
    float x[16]; load16f(Tk + R*72 + quad*16, x);
    float s=0.f;
    #pragma unroll
    for (int i=0;i<16;i++) s += x[i];
    s += __shfl_xor(s,16,64); s += __shfl_xor(s,32,64);
    float m = s*(1.f/64.f), q=0.f;
    #pragma unroll
    for (int i=0;i<16;i++){ float d=x[i]-m; q=fmaf(d,d,q); }
    q += __shfl_xor(q,16,64); q += __shfl_xor(q,32,64);
    float rs = __builtin_amdgcn_rsqf(q*(1.f/64.f)+1e-6f);
    v8bf o0,o1;
    #pragma unroll
    for (int i=0;i<8;i++){
      o0[i]=(__bf16)((x[i]  -m)*rs*s1f[i]  +b1f[i]);
      o1[i]=(__bf16)((x[8+i]-m)*rs*s1f[8+i]+b1f[8+i]);
    }
    *(v8bf*)(Ab+R*136+quad*16)=o0; *(v8bf*)(Ab+R*136+quad*16+8)=o1;
  }
  BAR();   // S1

  auto actAb = [&](int mt,int kt,int r,int q){ return *(const v8bf*)(Ab + (size_t)(mt*16+r)*136 + q*8 + kt*32); };
  auto actBb = [&](int mt,int kt,int r,int q){ return *(const v8bf*)(Bb + (size_t)(mt*16+r)*136 + q*8 + kt*32); };
  auto actTk = [&](int mt,int kt,int r,int q){ return *(const v8bf*)(Tk + (size_t)(mt*16+r)*72  + q*8 + kt*32); };

  // ---- QKV fused (one act read feeds K,V,Q): K -> Bb[:,64:], V -> Ab[:,64:],
  //      Q -> Bb[:,0:64] ----
  gemmF<2,4,3>(actAb, wfQKV, wv, lane,
    [&](int w,int wb,int mt,int r,v4f c){ v4bf o;
      #pragma unroll
      for (int k=0;k<4;k++) o[k]=(__bf16)c[k];
      __bf16* d = (w==0)? &Bb[(mt*16+r)*136+64+wb]
               : (w==1)? &Ab[(mt*16+r)*136+64+wb]
                       : &Bb[(mt*16+r)*136+wb];
      *(v4bf*)d = o; });
  auto wfO = wload<2,1>(ws+W_A1O, a.a1_ob, wv, lane);   // survives S2+S3
  BAR();   // S2

  // ---- attn weights + attn@V (wave-local tokens) ----
  if (lane<60){
    int tg=lane/20, rem=lane-tg*20, h=rem/5, i=rem-h*5;
    int T=3*wv+tg;
    bool mi = (float)msfb[T*5+i]>0.5f;
    float qv[16]; load16f(&Bb[(T*5+i)*136 + h*16], qv);
    float lgv[5], mx=NEG_INF_F;
    #pragma unroll
    for (int j=0;j<5;j++){
      float kk[16]; load16f(&Bb[(T*5+j)*136 + 64 + h*16], kk);
      float d=0.f;
      #pragma unroll
      for (int dd=0;dd<16;dd++) d += qv[dd]*kk[dd];
      bool mj = (float)msfb[T*5+j]>0.5f;
      lgv[j] = (mi&&mj)? d*0.25f : NEG_INF_F;
      mx = fmaxf(mx,lgv[j]);
    }
    float sum=0.f, ex[5];
    #pragma unroll
    for (int j=0;j<5;j++){ ex[j]=__expf(lgv[j]-mx); sum+=ex[j]; }
    float inv=1.0f/sum;
    #pragma unroll
    for (int j=0;j<5;j++) ATTb[T*128 + h*32 + i*5+j]=(__bf16)(ex[j]*inv);
  }
  {
    int h = lane>>4;
    #pragma unroll
    for (int tg=0; tg<3; tg++){
      int T=3*wv+tg;
      float v5[5];
      #pragma unroll
      for (int j=0;j<5;j++) v5[j] = (float)Ab[(T*5+j)*136+64+lane];
      const __bf16* wp = ATTb + T*128 + h*32;
      v8bf w0v = *(const v8bf*)(wp);
      v8bf w1v = *(const v8bf*)(wp+8);
      v8bf w2v = *(const v8bf*)(wp+16);
      v8bf w3v = *(const v8bf*)(wp+24);
      float wf[32];
      #pragma unroll
      for (int k=0;k<8;k++){
        wf[k]=(float)w0v[k]; wf[8+k]=(float)w1v[k];
        wf[16+k]=(float)w2v[k]; wf[24+k]=(float)w3v[k];
      }
      #pragma unroll
      for (int i=0;i<5;i++){
        float o=0.f;
        #pragma unroll
        for (int j=0;j<5;j++) o += wf[i*5+j]*v5[j];
        Ab[(T*5+i)*136+lane]=(__bf16)o;
      }
    }
  }
  BAR();   // S3

  // ---- o-proj + residual -> Tk (col-slices) ----
  gemmW<2,4,1>(actAb, wfO, wv, lane,
    [&](int wb,int mt,int r,v4f c){
      int R=mt*16+r; float mm=(float)mfb[R];
      v4bf old=*(const v4bf*)&Tk[R*72+wb]; v4bf o;
      #pragma unroll
      for (int k=0;k<4;k++) o[k]=(__bf16)((float)old[k]+c[k]*mm);
      *(v4bf*)&Tk[R*72+wb]=o; });
  auto wfM1 = wload<2,2>(ws+W_M1, a.m1_b, wv, lane);    // survives S4+S5
  float s2f[16], b2f[16];                                // ln2 params cross S4
  load16p(a.ln2_s + quad*16, s2f);
  load16p(a.ln2_b + quad*16, b2f);
  BAR();   // S4

  // ---- ln2 -> Ab[:,0:64] (own rows) ----
  if (ar<15){
    int R = 15*wv + ar;
    float x[16]; load16f(Tk + R*72 + quad*16, x);
    float s=0.f;
    #pragma unroll
    for (int i=0;i<16;i++) s += x[i];
    s += __shfl_xor(s,16,64); s += __shfl_xor(s,32,64);
    float m = s*(1.f/64.f), q=0.f;
    #pragma unroll
    for (int i=0;i<16;i++){ float d=x[i]-m; q=fmaf(d,d,q); }
    q += __shfl_xor(q,16,64); q += __shfl_xor(q,32,64);
    float rs = __builtin_amdgcn_rsqf(q*(1.f/64.f)+1e-6f);
    v8bf o0,o1;
    #pragma unroll
    for (int i=0;i<8;i++){
      o0[i]=(__bf16)((x[i]  -m)*rs*s2f[i]  +b2f[i]);
      o1[i]=(__bf16)((x[8+i]-m)*rs*s2f[8+i]+b2f[8+i]);
    }
    *(v8bf*)(Ab+R*136+quad*16)=o0; *(v8bf*)(Ab+R*136+quad*16+8)=o1;
  }
  BAR();   // S5

  // ---- m1 -> Bb[:,0:128] ----
  gemmW<2,4,2>(actAb, wfM1, wv, lane,
    [&](int wb,int mt,int r,v4f c){ v4bf o;
      #pragma unroll
      for (int k=0;k<4;k++) o[k]=(__bf16)gelu_f(c[k]);
      *(v4bf*)&Bb[(mt*16+r)*136+wb]=o; });
  auto wfM2 = wload<4,2>(ws+W_M2, a.m2_b, wv, lane);
  BAR();   // S6
  // ---- m2 -> Ab[:,0:128] ----
  gemmW<4,4,2>(actBb, wfM2, wv, lane,
    [&](int wb,int mt,int r,v4f c){ v4bf o;
      #pragma unroll
      for (int k=0;k<4;k++) o[k]=(__bf16)gelu_f(c[k]);
      *(v4bf*)&Ab[(mt*16+r)*136+wb]=o; });
  auto wfM3 = wload<4,1>(ws+W_M3, a.m3_b, wv, lane);
  auto wfE1 = wload<1,2>(ws+W_E1, a.e1_b, wv, lane);
  BAR();   // S7
  // ---- m3 -> Tk (resid*mask) ; e1 (token-level) -> Bb rows 0..15 ----
  gemmW<4,4,1>(actAb, wfM3, wv, lane,
    [&](int wb,int mt,int r,v4f c){
      int R=mt*16+r; float mm=(float)mfb[R];
      v4bf old=*(const v4bf*)&Tk[R*72+wb]; v4bf o;
      #pragma unroll
      for (int k=0;k<4;k++) o[k]=(__bf16)(((float)old[k]+c[k]*mm)*mm);
      *(v4bf*)&Tk[R*72+wb]=o; });
  gemmW<1,1,2>([&](int,int,int r,int q){ return *(const v8bf*)(Eg + (size_t)r*40 + q*8); },
    wfE1, wv, lane,
    [&](int wb,int mt,int r,v4f c){ v4bf o;
      #pragma unroll
      for (int k=0;k<4;k++) o[k]=(__bf16)gelu_f(c[k]);
      *(v4bf*)&Bb[r*136+wb]=o; });
  auto wfE2 = wload<4,2>(ws+W_E2, a.e2_b, wv, lane);
  BAR();   // S8
  // ---- e2 -> Ab rows 0..15 ----
  gemmW<4,1,2>(actBb, wfE2, wv, lane,
    [&](int wb,int mt,int r,v4f c){ v4bf o;
      #pragma unroll
      for (int k=0;k<4;k++) o[k]=(__bf16)gelu_f(c[k]);
      *(v4bf*)&Ab[r*136+wb]=o; });
  auto wfE3 = wload<4,1>(ws+W_E3, a.e3_b, wv, lane);
  BAR();   // S9
  // ---- e3 -> ECX rows 0..15 ----
  gemmW<4,1,1>(actAb, wfE3, wv, lane,
    [&](int wb,int mt,int r,v4f c){ v4bf o;
      #pragma unroll
      for (int k=0;k<4;k++) o[k]=(__bf16)c[k];
      *(v4bf*)&ECX[r*64+wb]=o; });
  auto wfL1 = wload<4,2>(ws+W_L1, a.l1_b, wv, lane);
  BAR();   // S10
  // ---- l1 (act = [Tk | ECX(token)]) -> Bb[:,0:128] ----
  gemmW<4,4,2>([&](int mt,int kt,int r,int q){
      int R=mt*16+r;
      return (kt<2) ? *(const v8bf*)(Tk + (size_t)R*72 + q*8 + kt*32)
                    : *(const v8bf*)(ECX + (size_t)((R*205)>>10)*64 + q*8 + (kt-2)*32); },
    wfL1, wv, lane,
    [&](int wb,int mt,int r,v4f c){ v4bf o;
      #pragma unroll
      for (int k=0;k<4;k++) o[k]=(__bf16)gelu_f(c[k]);
      *(v4bf*)&Bb[(mt*16+r)*136+wb]=o; });
  auto wfL2 = wload<4,2>(ws+W_L2, a.l2_b, wv, lane);
  BAR();   // S11
  // ---- l2 -> Ab[:,0:128] ----
  gemmW<4,4,2>(actBb, wfL2, wv, lane,
    [&](int wb,int mt,int r,v4f c){ v4bf o;
      #pragma unroll
      for (int k=0;k<4;k++) o[k]=(__bf16)gelu_f(c[k]);
      *(v4bf*)&Ab[(mt*16+r)*136+wb]=o; });
  const __bf16* WsPKV[2] = {ws+W_PK, ws+W_PV};
  const float*  bsPKV[2] = {a.p_kb, a.p_vb};
  auto wfPKV = wloadF<2,2>(WsPKV, bsPKV, wv, lane);
  float l3f[32];                                   // l3 weights cross S12
  load16p(a.l3_w + quad*32, l3f);
  load16p(a.l3_w + quad*32 + 16, l3f+16);
  float l3b = a.l3_b[0];
  BAR();   // S12

  // ---- l3 (own rows) + alpha + v_r/v_u ; kp/vp fused -> Bb ----
  if (ar<15){
    int R = 15*wv + ar;
    float x[16], y[16];
    load16f(&Ab[R*136 + quad*32], x);
    load16f(&Ab[R*136 + quad*32 + 16], y);
    float p = 0.f;
    #pragma unroll
    for (int i=0;i<16;i++) p = fmaf(x[i], l3f[i], p);
    #pragma unroll
    for (int i=0;i<16;i++) p = fmaf(y[i], l3f[16+i], p);
    p += __shfl_xor(p,16,64); p += __shfl_xor(p,32,64);
    if (quad==0) lga[R] = p + l3b;
  }
  gemmF<2,4,2>(actTk, wfPKV, wv, lane,
    [&](int w,int wb,int mt,int r,v4f c){ v4bf o;
      #pragma unroll
      for (int k=0;k<4;k++) o[k]=(__bf16)c[k];
      *(v4bf*)&Bb[(mt*16+r)*136 + (w?64:0) + wb] = o; });
  if (lane<3){
    int T=3*wv+lane;
    float ml[5], mx=-1e9f;
    #pragma unroll
    for (int i=0;i<5;i++){ ml[i]=((float)mfb[T*5+i]>0.5f)? lga[T*5+i] : -1e9f; mx=fmaxf(mx,ml[i]); }
    float den=0.f, e[5];
    #pragma unroll
    for (int i=0;i<5;i++){ e[i]=__expf(ml[i]-mx)*(float)mfb[T*5+i]; den+=e[i]; }
    float inv=1.0f/(den+1e-9f);
    #pragma unroll
    for (int i=0;i<5;i++) lga[T*5+i]=e[i]*inv;
  }
  if (lane<18){
    int tg=lane/6, c=lane-tg*6;
    int T=3*wv+tg;
    float v=0.f;
    #pragma unroll
    for (int i=0;i<5;i++) v += lga[T*5+i]*(float)Ru[T*30+i*6+c];
    long tk = blkT0 + T;
    if (tk<ntok) a.out[tk*134+128+c]=v;
  }
  float qvh[16];                                   // pool query crosses S13
  load16p((const float*)(ws + W_QP) + (lane&3)*16, qvh);
  BAR();   // S13

  // ---- pooling attn + pooled-o (wave-local tokens) ----
  if (lane<12){
    int tg=lane>>2, h=lane&3;
    int T=3*wv+tg;
    float lgv[5], mx=NEG_INF_F;
    #pragma unroll
    for (int j=0;j<5;j++){
      float kk[16]; load16f(&Bb[(T*5+j)*136 + h*16], kk);
      float d=0.f;
      #pragma unroll
      for (int dd=0;dd<16;dd++) d += qvh[dd]*kk[dd];
      lgv[j] = ((float)msfb[T*5+j]>0.5f)? d*0.25f : NEG_INF_F;
      mx = fmaxf(mx,lgv[j]);
    }
    float sum=0.f, ex[5];
    #pragma unroll
    for (int j=0;j<5;j++){ ex[j]=__expf(lgv[j]-mx); sum+=ex[j]; }
    float inv=1.0f/sum;
    #pragma unroll
    for (int j=0;j<5;j++) pattn[T*32+h*8+j]=ex[j]*inv;
  }
  for (int it=lane; it<192; it+=64){
    int tg=it>>6, c=it&63, h=c>>4;
    int T=3*wv+tg;
    const float* pp2 = pattn + T*32 + h*8;
    float4 p4 = *(const float4*)pp2;
    float p4v = pp2[4];
    float o=0.f;
    o += p4.x*(float)Bb[(T*5+0)*136+64+c];
    o += p4.y*(float)Bb[(T*5+1)*136+64+c];
    o += p4.z*(float)Bb[(T*5+2)*136+64+c];
    o += p4.w*(float)Bb[(T*5+3)*136+64+c];
    o += p4v *(float)Bb[(T*5+4)*136+64+c];
    Po[T*64+c]=(__bf16)o;
  }
  auto wfPO = wload<2,1>(ws+W_PO, a.p_ob, wv, lane);
  BAR();   // S14

  // ---- p_ow -> Cc (x many) ----
  gemmW<2,1,1>([&](int,int kt,int r,int q){ return *(const v8bf*)(Po + (size_t)r*64 + q*8 + kt*32); },
    wfPO, wv, lane,
    [&](int wb,int mt,int r,v4f c){
      float mm = many[r];
      v4bf o;
      #pragma unroll
      for (int k=0;k<4;k++) o[k]=(__bf16)(c[k]*mm);
      *(v4bf*)&Cc[r*64+wb]=o; });
  auto wfH1 = wload<5,2>(ws+W_H1, a.h1_b, wv, lane);
  BAR();   // S15

  // ---- h1 (act = [Eg | Cc | Pe], K=160) -> Bb rows 0..15 ----
  gemmW<5,1,2>([&](int,int kt,int r,int q){
      if (kt==0) return *(const v8bf*)(Eg + (size_t)r*40 + q*8);
      if (kt<3)  return *(const v8bf*)(Cc + (size_t)r*64 + q*8 + (kt-1)*32);
      return *(const v8bf*)(Pe + (size_t)r*64 + q*8 + (kt-3)*32); },
    wfH1, wv, lane,
    [&](int wb,int mt,int r,v4f c){ v4bf o;
      #pragma unroll
      for (int k=0;k<4;k++) o[k]=(__bf16)gelu_f(c[k]);
      *(v4bf*)&Bb[r*136+wb]=o; });
  auto wfH2 = wload<4,2>(ws+W_H2, a.h2_b, wv, lane);
  BAR();   // S16
  // ---- h2 -> Ab rows 0..15 ----
  gemmW<4,1,2>(actBb, wfH2, wv, lane,
    [&](int wb,int mt,int r,v4f c){ v4bf o;
      #pragma unroll
      for (int k=0;k<4;k++) o[k]=(__bf16)gelu_f(c[k]);
      *(v4bf*)&Ab[r*136+wb]=o; });
  auto wfH3 = wload<4,2>(ws+W_H3, a.h3_b, wv, lane);
  BAR();   // S17
  // ---- h3 -> out ----
  gemmW<4,1,2>(actAb, wfH3, wv, lane,
    [&](int wb,int mt,int r,v4f c){
      long tk = blkT0 + r;
      if (r<12 && tk<ntok){
        float2* o2 = (float2*)&a.out[tk*134 + wb];
        o2[0] = make_float2(c[0], c[1]);
        o2[1] = make_float2(c[2], c[3]);
      } });
}

extern "C" void kernel_launch(void* const* d_in, const int* in_sizes, int n_in,
                              void* d_out, int out_size, void* d_ws, size_t ws_size,
                              hipStream_t stream)
{
  P a;
  const float** pp = reinterpret_cast<const float**>(&a);
  for (int i=0;i<50;i++) pp[i] = reinterpret_cast<const float*>(d_in[i]);
  a.out = reinterpret_cast<float*>(d_out);
  int ntok = in_sizes[0] / DOBS;   // 65536

  __bf16* ws = reinterpret_cast<__bf16*>(d_ws);
  hipLaunchKernelGGL(prep_w, dim3(173), dim3(256), 0, stream, a, ws);
  hipLaunchKernelGGL(swarm_mfma, dim3((ntok+11)/12), dim3(256), 0, stream, a, ws, ntok);
}

// Round 13
// 463.242 us; speedup vs baseline: 1.0790x; 1.0138x over previous
//
#include <hip/hip_runtime.h>
#include <math.h>

// SwarmSetEquivariantTorso — bf16 MFMA, N-split block GEMMs, 12 tok/block.
// HISTORY: R0 375us | R5 463 (weight-batch poison) | R7 437 (occupancy no)
// R8 361 (WIN weight prefetch over non-draining BAR) | R9 363.6 (NEUTRAL)
// R10 354 (WIN act-read reuse) | R11 339 (WIN attn/pool LDS vectorize)
// R12 333 (WIN param-load hoisting).
// THIS = R12 + two glue shaves in the proven families:
//  (1) setup loops restructured tg-nested: kills per-iteration magic-mul
//      divisions (/117,/50,/30) at equal-or-fewer iterations;
//  (2) pooling attn wave-parallel: 60 lanes = one (T,h,j) dot each (was
//      12 lanes x 5 serial dots); exchange via wave-local pattn + in-wave
//      s_waitcnt lgkmcnt(0) (writer/reader same wave -> no barrier).

#define DOBS 198
#define NEG_INF_F (-3.402823466e38f)

// Non-draining barrier: LDS visibility via lgkmcnt(0); global (weight)
// loads stay in flight. No cross-wave global communication in-kernel.
#define BAR() do { asm volatile("s_waitcnt lgkmcnt(0)" ::: "memory"); \
                   __builtin_amdgcn_s_barrier(); } while(0)
// In-wave LDS fence: wave-wide ds ops retire before later reads (lockstep).
#define WAVE_LDS_FENCE() asm volatile("s_waitcnt lgkmcnt(0)" ::: "memory")

typedef __bf16 v8bf __attribute__((ext_vector_type(8)));
typedef __bf16 v4bf __attribute__((ext_vector_type(4)));
typedef float  v4f  __attribute__((ext_vector_type(4)));

struct P {
  const float *obs,*tok_w,*tok_b,*ln1_s,*ln1_b,
    *a1_qw,*a1_qb,*a1_kw,*a1_kb,*a1_vw,*a1_vb,*a1_ow,*a1_ob,
    *ln2_s,*ln2_b,*m1_w,*m1_b,*m2_w,*m2_b,*m3_w,*m3_b,
    *e1_w,*e1_b,*e2_w,*e2_b,*e3_w,*e3_b,
    *l1_w,*l1_b,*l2_w,*l2_b,*l3_w,*l3_b,
    *seed,*p_qw,*p_qb,*p_kw,*p_kb,*p_vw,*p_vb,*p_ow,*p_ob,
    *pr_w,*pr_b,*h1_w,*h1_b,*h2_w,*h2_b,*h3_w,*h3_b;
  float* out;
};
static_assert(sizeof(P) == 51*sizeof(void*), "P layout");

// ws bf16 weight image, W_t[n][k] per matrix (element offsets)
#define W_A1Q 0
#define W_A1K 4096
#define W_A1V 8192
#define W_A1O 12288
#define W_M1  16384
#define W_M2  24576
#define W_M3  40960
#define W_E1  49152
#define W_E2  53248
#define W_E3  69632
#define W_L1  77824
#define W_L2  94208
#define W_PK  110592
#define W_PV  114688
#define W_PO  118784
#define W_H1  122880
#define W_H2  143360
#define W_H3  159744
#define W_END 176128
#define W_QP  176128   // + 64 f32 (pooling query, precomputed)

__global__ __launch_bounds__(256)
void prep_w(P a, __bf16* ws)
{
  if (blockIdx.x == 172){
    int t = threadIdx.x;
    if (t < 64){
      float acc = a.p_qb[t];
      for (int k=0;k<64;k++) acc += a.seed[k]*a.p_qw[k*64+t];
      ((float*)(ws + W_QP))[t] = acc;
    }
    return;
  }
  const float* srcs[18] = {a.a1_qw,a.a1_kw,a.a1_vw,a.a1_ow,a.m1_w,a.m2_w,a.m3_w,
                           a.e1_w,a.e2_w,a.e3_w,a.l1_w,a.l2_w,a.p_kw,a.p_vw,a.p_ow,
                           a.h1_w,a.h2_w,a.h3_w};
  const int Ks[18]   = {64,64,64,64,64,128,128,32,128,128,128,128,64,64,64,160,128,128};
  const int Ns[18]   = {64,64,64,64,128,128,64,128,128,64,128,128,64,64,64,128,128,128};
  const int offs[18] = {W_A1Q,W_A1K,W_A1V,W_A1O,W_M1,W_M2,W_M3,W_E1,W_E2,W_E3,
                        W_L1,W_L2,W_PK,W_PV,W_PO,W_H1,W_H2,W_H3};
  __shared__ float tile[32][33];
  int b = blockIdx.x, m = 0, acc = 0;
  for (; m < 18; m++){
    int t = (Ks[m]/32)*(Ns[m]/32);
    if (b < acc + t) break;
    acc += t;
  }
  int lt = b - acc, K = Ks[m], N = Ns[m];
  int ntile = N/32, kt = lt/ntile, nt = lt%ntile;
  int tx = threadIdx.x & 31, ty = threadIdx.x >> 5;
  const float* S = srcs[m];
  #pragma unroll
  for (int rr=0; rr<32; rr+=8)
    tile[ty+rr][tx] = S[(size_t)(kt*32+ty+rr)*N + nt*32+tx];
  __syncthreads();
  __bf16* D = ws + offs[m];
  #pragma unroll
  for (int rr=0; rr<32; rr+=8)
    D[(size_t)(nt*32+ty+rr)*K + kt*32+tx] = (__bf16)tile[tx][ty+rr];
}

// gelu(x) = x * sigmoid(2t),  t = 0.79788456(x + 0.044715 x^3)  (exact tanh form)
__device__ __forceinline__ float gelu_f(float x){
  float t = x * fmaf(0.0356774081f, x*x, 0.7978845608f);
  float u = __builtin_amdgcn_exp2f(-2.885390082f * t);
  return x * __builtin_amdgcn_rcpf(1.0f + u);
}

__device__ __forceinline__ void load16f(const __bf16* p, float* f){
  v8bf a = *(const v8bf*)p, b = *(const v8bf*)(p+8);
  #pragma unroll
  for (int i=0;i<8;i++){ f[i]=(float)a[i]; f[8+i]=(float)b[i]; }
}

// 16 f32 params as 4x float4 into constant-indexed regs.
__device__ __forceinline__ void load16p(const float* p, float* f){
  #pragma unroll
  for (int i=0;i<4;i++){
    float4 v = *(const float4*)(p + i*4);
    f[i*4+0]=v.x; f[i*4+1]=v.y; f[i*4+2]=v.z; f[i*4+3]=v.w;
  }
}

// Weight fragments, issued early (prefetch), consumed after next barrier.
template<int KT,int NTPW> struct WF {
  v8bf  w[NTPW][KT];
  float4 b[NTPW];
};

// N-split loader: wave wv's NTPW consecutive N-tiles of one matrix.
template<int KT,int NTPW>
__device__ __forceinline__ WF<KT,NTPW> wload(const __bf16* __restrict__ Wt,
    const float* __restrict__ bias, int wv, int lane)
{
  WF<KT,NTPW> f;
  const int ar = lane&15, quad = lane>>4;
  #pragma unroll
  for (int ln=0; ln<NTPW; ln++){
    const int wt = wv*NTPW + ln;
    const __bf16* wp = Wt + (size_t)(wt*16+ar)*(KT*32) + quad*8;
    #pragma unroll
    for (int kt=0;kt<KT;kt++) f.w[ln][kt] = *(const v8bf*)(wp + kt*32);
    f.b[ln] = *(const float4*)(bias + wt*16 + quad*4);
  }
  return f;
}

// Fused-matrix loader: wave wv's N-tile (tile index wv) of NW matrices.
template<int KT,int NW>
__device__ __forceinline__ WF<KT,NW> wloadF(const __bf16* const* Ws,
    const float* const* bs, int wv, int lane)
{
  WF<KT,NW> f;
  const int ar = lane&15, quad = lane>>4;
  #pragma unroll
  for (int w=0; w<NW; w++){
    const __bf16* wp = Ws[w] + (size_t)(wv*16+ar)*(KT*32) + quad*8;
    #pragma unroll
    for (int kt=0;kt<KT;kt++) f.w[w][kt] = *(const v8bf*)(wp + kt*32);
    f.b[w] = *(const float4*)(bs[w] + wv*16 + quad*4);
  }
  return f;
}

// N-split GEMM, act-reuse order: one act read per (mt,kt) feeds all NTPW
// N-tile accumulators. Weights already in regs (prefetched).
template<int KT,int MT,int NTPW,typename LA,typename E>
__device__ __forceinline__ void gemmW(LA la, const WF<KT,NTPW>& f,
    int wv, int lane, E epi)
{
  const int ar = lane&15, quad = lane>>4;
  #pragma unroll
  for (int mt=0; mt<MT; mt++){
    v4f c[NTPW];
    #pragma unroll
    for (int ln=0;ln<NTPW;ln++){
      c[ln][0]=f.b[ln].x; c[ln][1]=f.b[ln].y; c[ln][2]=f.b[ln].z; c[ln][3]=f.b[ln].w;
    }
    #pragma unroll
    for (int kt=0;kt<KT;kt++){
      v8bf av = la(mt,kt,ar,quad);
      #pragma unroll
      for (int ln=0;ln<NTPW;ln++)
        c[ln] = __builtin_amdgcn_mfma_f32_16x16x32_bf16(f.w[ln][kt], av, c[ln], 0,0,0);
    }
    #pragma unroll
    for (int ln=0;ln<NTPW;ln++)
      epi((wv*NTPW+ln)*16 + quad*4, mt, ar, c[ln]);
  }
}

// Fused-matrix GEMM: one act read per (mt,kt) feeds NW matrices' tiles.
// epi(w, wb, mt, ar, c) — wb = wv*16+quad*4 within matrix w.
template<int KT,int MT,int NW,typename LA,typename E>
__device__ __forceinline__ void gemmF(LA la, const WF<KT,NW>& f,
    int wv, int lane, E epi)
{
  const int ar = lane&15, quad = lane>>4;
  #pragma unroll
  for (int mt=0; mt<MT; mt++){
    v4f c[NW];
    #pragma unroll
    for (int w=0;w<NW;w++){
      c[w][0]=f.b[w].x; c[w][1]=f.b[w].y; c[w][2]=f.b[w].z; c[w][3]=f.b[w].w;
    }
    #pragma unroll
    for (int kt=0;kt<KT;kt++){
      v8bf av = la(mt,kt,ar,quad);
      #pragma unroll
      for (int w=0;w<NW;w++)
        c[w] = __builtin_amdgcn_mfma_f32_16x16x32_bf16(f.w[w][kt], av, c[w], 0,0,0);
    }
    #pragma unroll
    for (int w=0;w<NW;w++)
      epi(w, wv*16 + quad*4, mt, ar, c[w]);
  }
}

// LDS map (bytes), total 53120 <= 53248 (proven 3 blocks/CU):
//  Ab   @0      bf16[64][136] 17408  (early: Df f32[12][32])
//  Bb   @17408  bf16[64][136] 17408  (early: TOKIN f32[60][12])
//  Tk   @34816  bf16[64][72]   9216  (early: OBSf f32[12][120]; late: Po bf16[12][64])
//  Pe   @44032  bf16[16][64]   2048
//  Eg   @46080  bf16[16][40]   1280
//  Ru   @47360  bf16[12][30]    736
//  mfb  @48096  bf16[64]        128
//  msfb @48224  bf16[64]        128
//  many @48352  f32[16]          64
//  lga  @48416  f32[64]         256
//  region @48672..53120 (4448 B), phase-overlaid:
//    S2-S3:  ATTb bf16[12][128] 3072 (padded [T][h][32])
//    S9-S11: ECX  bf16[16][64]  2048
//    S13-14: pattn f32[12][32]  1536 (padded [T][h][8])
//    S14-16: Cc   bf16[16][64]  2048 @50720
__global__ __launch_bounds__(256,3)
void swarm_mfma(P a, const __bf16* __restrict__ ws, int ntok)
{
  __shared__ char smem[53120] __attribute__((aligned(16)));
  __bf16* Ab   = (__bf16*)(smem);
  __bf16* Bb   = (__bf16*)(smem+17408);
  float*  TOKIN= (float*) (smem+17408);
  __bf16* Tk   = (__bf16*)(smem+34816);
  float*  OBSf = (float*) (smem+34816);
  __bf16* Po   = (__bf16*)(smem+34816);
  __bf16* Pe   = (__bf16*)(smem+44032);
  __bf16* Eg   = (__bf16*)(smem+46080);
  __bf16* Ru   = (__bf16*)(smem+47360);
  __bf16* mfb  = (__bf16*)(smem+48096);
  __bf16* msfb = (__bf16*)(smem+48224);
  float*  many = (float*) (smem+48352);
  float*  lga  = (float*) (smem+48416);
  __bf16* ECX  = (__bf16*)(smem+48672);
  __bf16* ATTb = (__bf16*)(smem+48672);   // [T][h][32] bf16, S2-S3 only
  float*  pattn= (float*) (smem+48672);   // [T][h][8] f32, S13-S14 only
  __bf16* Cc   = (__bf16*)(smem+50720);

  const int lane = threadIdx.x & 63;
  const int wv   = threadIdx.x >> 6;
  const int ar   = lane & 15, quad = lane >> 4;
  const long blkT0 = (long)blockIdx.x*12;

  // ================= setup (wave-local tokens 3wv..3wv+2) =================
  // tg-nested loops: no per-iteration magic-mul divisions.
  #pragma unroll
  for (int tg=0; tg<3; tg++){
    long gt = blkT0 + 3*wv + tg; if (gt>ntok-1) gt=ntok-1;
    const float* src = a.obs + gt*DOBS;
    float* dst = OBSf + (3*wv+tg)*120;
    for (int c=lane; c<117; c+=64) dst[c] = src[c];
  }
  float* Df = (float*)Ab;
  #pragma unroll
  for (int tg=0; tg<3; tg++){
    if (lane<25){
      int i=lane/5, j=lane-i*5;
      const float* ob = OBSf + (3*wv+tg)*120 + 32;
      float d2=0.f;
      #pragma unroll
      for (int d=0;d<3;d++){
        float ri=ob[15*i+d]; ri = isfinite(ri)?ri:0.f;
        float rj=ob[15*j+d]; rj = isfinite(rj)?rj:0.f;
        float df=ri-rj; d2 += df*df;
      }
      Df[(3*wv+tg)*32+lane]=sqrtf(d2);
    }
  }
  if (lane<15){
    int T=3*wv+lane/5, s=lane%5;
    const float* b = OBSf + T*120 + 32 + 15*s;
    mfb[15*wv+lane] = (__bf16)((fabsf(b[0])>1e-6f||fabsf(b[1])>1e-6f||fabsf(b[2])>1e-6f)?1.f:0.f);
  }
  if (wv==0 && lane>=60){ mfb[lane]=(__bf16)0.f; msfb[lane]=(__bf16)0.f; }
  if (wv==0 && lane>=12 && lane<16) many[lane]=0.f;
  if (lane<3){
    int T=3*wv+lane;
    float any = (float)mfb[T*5]+(float)mfb[T*5+1]+(float)mfb[T*5+2]+(float)mfb[T*5+3]+(float)mfb[T*5+4];
    float anyf = (any>0.f)?1.f:0.f; many[T]=anyf;
    #pragma unroll
    for (int i=0;i<5;i++) msfb[T*5+i] = (anyf>0.f)? mfb[T*5+i] : (__bf16)((i==0)?1.f:0.f);
  }
  if (lane<15){
    int T=3*wv+lane/5, i=lane%5, R=15*wv+lane;
    float dmin=1e9f,dsum=0.f,cnt=0.f;
    #pragma unroll
    for (int j=0;j<5;j++){
      if (j!=i && (float)mfb[T*5+i]>0.5f && (float)mfb[T*5+j]>0.5f){
        float dd=Df[T*32+i*5+j];
        dmin=fminf(dmin,dd); dsum+=dd; cnt+=1.f;
      }
    }
    TOKIN[R*12+10]=dmin;
    TOKIN[R*12+11]=(cnt>0.f)? dsum/(cnt+1e-9f) : 0.f;
  }
  #pragma unroll
  for (int tg=0; tg<3; tg++){
    if (lane<50){
      int s=lane/10, c=lane-s*10;
      int T=3*wv+tg;
      const float* b = OBSf + T*120 + 32 + 15*s;
      float v;
      if (c<4)        v=b[11+c];
      else if (c==4)  v=b[9];
      else if (c==5)  v=b[10];
      else if (c<9)   v=b[6+(c-6)];
      else { float a0=b[6],a1=b[7],a2=b[8]; v=sqrtf(a0*a0+a1*a1+a2*a2); }
      TOKIN[(T*5+s)*12+c]=v;
    }
  }
  for (int it=lane; it<96; it+=64){
    int tg=it>>5, c=it&31;
    Eg[(3*wv+tg)*40+c] = (__bf16)OBSf[(3*wv+tg)*120+c];
  }
  #pragma unroll
  for (int tg=0; tg<3; tg++){
    if (lane<30){
      int T=3*wv+tg;
      Ru[T*30+lane] = (__bf16)OBSf[T*120+32+15*(lane/6)+(lane%6)];
    }
  }
  for (int it=lane; it<192; it+=64){
    int tg=it>>6, c=it&63;
    float acc = a.pr_b[c];
    #pragma unroll
    for (int k=0;k<10;k++) acc += OBSf[(3*wv+tg)*120+107+k]*a.pr_w[k*64+c];
    Pe[(3*wv+tg)*64+c] = (__bf16)gelu_f(acc);
  }
  // hoisted params (R8 family): loads cross S0, consumed in tok-embed/ln1
  float w0[12];
  #pragma unroll
  for (int k=0;k<12;k++) w0[k] = a.tok_w[k*64+lane];
  float tb = a.tok_b[lane];
  float s1f[16], b1f[16];
  load16p(a.ln1_s + quad*16, s1f);
  load16p(a.ln1_b + quad*16, b1f);
  BAR();   // S0: OBSf/Df/TOKIN producers done; Tk writes may begin

  // prefetch QKV weights (fused: 3 matrices, this wave's N-tile of each);
  // loads overlap tok-embed + ln1 and cross S1.
  const __bf16* WsQKV[3] = {ws+W_A1K, ws+W_A1V, ws+W_A1Q};
  const float*  bsQKV[3] = {a.a1_kb, a.a1_vb, a.a1_qb};
  auto wfQKV = wloadF<2,3>(WsQKV, bsQKV, wv, lane);

  // ---- P3: tok embed (fp32 K=12) -> Tk rows 15wv..15wv+14; then ln1 -> Ab ----
  {
    for (int r=0;r<15;r++){
      int R = 15*wv + r;
      const float4* tin = (const float4*)(TOKIN + R*12);
      float4 x0 = tin[0], x1 = tin[1], x2 = tin[2];
      float acc = tb;
      acc=fmaf(x0.x,w0[0],acc); acc=fmaf(x0.y,w0[1],acc);
      acc=fmaf(x0.z,w0[2],acc); acc=fmaf(x0.w,w0[3],acc);
      acc=fmaf(x1.x,w0[4],acc); acc=fmaf(x1.y,w0[5],acc);
      acc=fmaf(x1.z,w0[6],acc); acc=fmaf(x1.w,w0[7],acc);
      acc=fmaf(x2.x,w0[8],acc); acc=fmaf(x2.y,w0[9],acc);
      acc=fmaf(x2.z,w0[10],acc); acc=fmaf(x2.w,w0[11],acc);
      Tk[R*72+lane] = (__bf16)(gelu_f(acc)*(float)mfb[R]);
    }
  }
  if (ar<15){   // ln1, own rows (shuffles stay within same-ar groups)
    int R = 15*wv + ar;
    float x[16]; load16f(Tk + R*72 + quad*16, x);
    float s=0.f;
    #pragma unroll
    for (int i=0;i<16;i++) s += x[i];
    s += __shfl_xor(s,16,64); s += __shfl_xor(s,32,64);
    float m = s*(1.f/64.f), q=0.f;
    #pragma unroll
    for (int i=0;i<16;i++){ float d=x[i]-m; q=fmaf(d,d,q); }
    q += __shfl_xor(q,16,64); q += __shfl_xor(q,32,64);
    float rs = __builtin_amdgcn_rsqf(q*(1.f/64.f)+1e-6f);
    v8bf o0,o1;
    #pragma unroll
    for (int i=0;i<8;i++){
      o0[i]=(__bf16)((x[i]  -m)*rs*s1f[i]  +b1f[i]);
      o1[i]=(__bf16)((x[8+i]-m)*rs*s1f[8+i]+b1f[8+i]);
    }
    *(v8bf*)(Ab+R*136+quad*16)=o0; *(v8bf*)(Ab+R*136+quad*16+8)=o1;
  }
  BAR();   // S1

  auto actAb = [&](int mt,int kt,int r,int q){ return *(const v8bf*)(Ab + (size_t)(mt*16+r)*136 + q*8 + kt*32); };
  auto actBb = [&](int mt,int kt,int r,int q){ return *(const v8bf*)(Bb + (size_t)(mt*16+r)*136 + q*8 + kt*32); };
  auto actTk = [&](int mt,int kt,int r,int q){ return *(const v8bf*)(Tk + (size_t)(mt*16+r)*72  + q*8 + kt*32); };

  // ---- QKV fused (one act read feeds K,V,Q): K -> Bb[:,64:], V -> Ab[:,64:],
  //      Q -> Bb[:,0:64] ----
  gemmF<2,4,3>(actAb, wfQKV, wv, lane,
    [&](int w,int wb,int mt,int r,v4f c){ v4bf o;
      #pragma unroll
      for (int k=0;k<4;k++) o[k]=(__bf16)c[k];
      __bf16* d = (w==0)? &Bb[(mt*16+r)*136+64+wb]
               : (w==1)? &Ab[(mt*16+r)*136+64+wb]
                       : &Bb[(mt*16+r)*136+wb];
      *(v4bf*)d = o; });
  auto wfO = wload<2,1>(ws+W_A1O, a.a1_ob, wv, lane);   // survives S2+S3
  BAR();   // S2

  // ---- attn weights + attn@V (wave-local tokens) ----
  if (lane<60){
    int tg=lane/20, rem=lane-tg*20, h=rem/5, i=rem-h*5;
    int T=3*wv+tg;
    bool mi = (float)msfb[T*5+i]>0.5f;
    float qv[16]; load16f(&Bb[(T*5+i)*136 + h*16], qv);
    float lgv[5], mx=NEG_INF_F;
    #pragma unroll
    for (int j=0;j<5;j++){
      float kk[16]; load16f(&Bb[(T*5+j)*136 + 64 + h*16], kk);
      float d=0.f;
      #pragma unroll
      for (int dd=0;dd<16;dd++) d += qv[dd]*kk[dd];
      bool mj = (float)msfb[T*5+j]>0.5f;
      lgv[j] = (mi&&mj)? d*0.25f : NEG_INF_F;
      mx = fmaxf(mx,lgv[j]);
    }
    float sum=0.f, ex[5];
    #pragma unroll
    for (int j=0;j<5;j++){ ex[j]=__expf(lgv[j]-mx); sum+=ex[j]; }
    float inv=1.0f/sum;
    #pragma unroll
    for (int j=0;j<5;j++) ATTb[T*128 + h*32 + i*5+j]=(__bf16)(ex[j]*inv);
  }
  {
    int h = lane>>4;
    #pragma unroll
    for (int tg=0; tg<3; tg++){
      int T=3*wv+tg;
      float v5[5];
      #pragma unroll
      for (int j=0;j<5;j++) v5[j] = (float)Ab[(T*5+j)*136+64+lane];
      const __bf16* wp = ATTb + T*128 + h*32;
      v8bf w0v = *(const v8bf*)(wp);
      v8bf w1v = *(const v8bf*)(wp+8);
      v8bf w2v = *(const v8bf*)(wp+16);
      v8bf w3v = *(const v8bf*)(wp+24);
      float wf[32];
      #pragma unroll
      for (int k=0;k<8;k++){
        wf[k]=(float)w0v[k]; wf[8+k]=(float)w1v[k];
        wf[16+k]=(float)w2v[k]; wf[24+k]=(float)w3v[k];
      }
      #pragma unroll
      for (int i=0;i<5;i++){
        float o=0.f;
        #pragma unroll
        for (int j=0;j<5;j++) o += wf[i*5+j]*v5[j];
        Ab[(T*5+i)*136+lane]=(__bf16)o;
      }
    }
  }
  BAR();   // S3

  // ---- o-proj + residual -> Tk (col-slices) ----
  gemmW<2,4,1>(actAb, wfO, wv, lane,
    [&](int wb,int mt,int r,v4f c){
      int R=mt*16+r; float mm=(float)mfb[R];
      v4bf old=*(const v4bf*)&Tk[R*72+wb]; v4bf o;
      #pragma unroll
      for (int k=0;k<4;k++) o[k]=(__bf16)((float)old[k]+c[k]*mm);
      *(v4bf*)&Tk[R*72+wb]=o; });
  auto wfM1 = wload<2,2>(ws+W_M1, a.m1_b, wv, lane);    // survives S4+S5
  float s2f[16], b2f[16];                                // ln2 params cross S4
  load16p(a.ln2_s + quad*16, s2f);
  load16p(a.ln2_b + quad*16, b2f);
  BAR();   // S4

  // ---- ln2 -> Ab[:,0:64] (own rows) ----
  if (ar<15){
    int R = 15*wv + ar;
    float x[16]; load16f(Tk + R*72 + quad*16, x);
    float s=0.f;
    #pragma unroll
    for (int i=0;i<16;i++) s += x[i];
    s += __shfl_xor(s,16,64); s += __shfl_xor(s,32,64);
    float m = s*(1.f/64.f), q=0.f;
    #pragma unroll
    for (int i=0;i<16;i++){ float d=x[i]-m; q=fmaf(d,d,q); }
    q += __shfl_xor(q,16,64); q += __shfl_xor(q,32,64);
    float rs = __builtin_amdgcn_rsqf(q*(1.f/64.f)+1e-6f);
    v8bf o0,o1;
    #pragma unroll
    for (int i=0;i<8;i++){
      o0[i]=(__bf16)((x[i]  -m)*rs*s2f[i]  +b2f[i]);
      o1[i]=(__bf16)((x[8+i]-m)*rs*s2f[8+i]+b2f[8+i]);
    }
    *(v8bf*)(Ab+R*136+quad*16)=o0; *(v8bf*)(Ab+R*136+quad*16+8)=o1;
  }
  BAR();   // S5

  // ---- m1 -> Bb[:,0:128] ----
  gemmW<2,4,2>(actAb, wfM1, wv, lane,
    [&](int wb,int mt,int r,v4f c){ v4bf o;
      #pragma unroll
      for (int k=0;k<4;k++) o[k]=(__bf16)gelu_f(c[k]);
      *(v4bf*)&Bb[(mt*16+r)*136+wb]=o; });
  auto wfM2 = wload<4,2>(ws+W_M2, a.m2_b, wv, lane);
  BAR();   // S6
  // ---- m2 -> Ab[:,0:128] ----
  gemmW<4,4,2>(actBb, wfM2, wv, lane,
    [&](int wb,int mt,int r,v4f c){ v4bf o;
      #pragma unroll
      for (int k=0;k<4;k++) o[k]=(__bf16)gelu_f(c[k]);
      *(v4bf*)&Ab[(mt*16+r)*136+wb]=o; });
  auto wfM3 = wload<4,1>(ws+W_M3, a.m3_b, wv, lane);
  auto wfE1 = wload<1,2>(ws+W_E1, a.e1_b, wv, lane);
  BAR();   // S7
  // ---- m3 -> Tk (resid*mask) ; e1 (token-level) -> Bb rows 0..15 ----
  gemmW<4,4,1>(actAb, wfM3, wv, lane,
    [&](int wb,int mt,int r,v4f c){
      int R=mt*16+r; float mm=(float)mfb[R];
      v4bf old=*(const v4bf*)&Tk[R*72+wb]; v4bf o;
      #pragma unroll
      for (int k=0;k<4;k++) o[k]=(__bf16)(((float)old[k]+c[k]*mm)*mm);
      *(v4bf*)&Tk[R*72+wb]=o; });
  gemmW<1,1,2>([&](int,int,int r,int q){ return *(const v8bf*)(Eg + (size_t)r*40 + q*8); },
    wfE1, wv, lane,
    [&](int wb,int mt,int r,v4f c){ v4bf o;
      #pragma unroll
      for (int k=0;k<4;k++) o[k]=(__bf16)gelu_f(c[k]);
      *(v4bf*)&Bb[r*136+wb]=o; });
  auto wfE2 = wload<4,2>(ws+W_E2, a.e2_b, wv, lane);
  BAR();   // S8
  // ---- e2 -> Ab rows 0..15 ----
  gemmW<4,1,2>(actBb, wfE2, wv, lane,
    [&](int wb,int mt,int r,v4f c){ v4bf o;
      #pragma unroll
      for (int k=0;k<4;k++) o[k]=(__bf16)gelu_f(c[k]);
      *(v4bf*)&Ab[r*136+wb]=o; });
  auto wfE3 = wload<4,1>(ws+W_E3, a.e3_b, wv, lane);
  BAR();   // S9
  // ---- e3 -> ECX rows 0..15 ----
  gemmW<4,1,1>(actAb, wfE3, wv, lane,
    [&](int wb,int mt,int r,v4f c){ v4bf o;
      #pragma unroll
      for (int k=0;k<4;k++) o[k]=(__bf16)c[k];
      *(v4bf*)&ECX[r*64+wb]=o; });
  auto wfL1 = wload<4,2>(ws+W_L1, a.l1_b, wv, lane);
  BAR();   // S10
  // ---- l1 (act = [Tk | ECX(token)]) -> Bb[:,0:128] ----
  gemmW<4,4,2>([&](int mt,int kt,int r,int q){
      int R=mt*16+r;
      return (kt<2) ? *(const v8bf*)(Tk + (size_t)R*72 + q*8 + kt*32)
                    : *(const v8bf*)(ECX + (size_t)((R*205)>>10)*64 + q*8 + (kt-2)*32); },
    wfL1, wv, lane,
    [&](int wb,int mt,int r,v4f c){ v4bf o;
      #pragma unroll
      for (int k=0;k<4;k++) o[k]=(__bf16)gelu_f(c[k]);
      *(v4bf*)&Bb[(mt*16+r)*136+wb]=o; });
  auto wfL2 = wload<4,2>(ws+W_L2, a.l2_b, wv, lane);
  BAR();   // S11
  // ---- l2 -> Ab[:,0:128] ----
  gemmW<4,4,2>(actBb, wfL2, wv, lane,
    [&](int wb,int mt,int r,v4f c){ v4bf o;
      #pragma unroll
      for (int k=0;k<4;k++) o[k]=(__bf16)gelu_f(c[k]);
      *(v4bf*)&Ab[(mt*16+r)*136+wb]=o; });
  const __bf16* WsPKV[2] = {ws+W_PK, ws+W_PV};
  const float*  bsPKV[2] = {a.p_kb, a.p_vb};
  auto wfPKV = wloadF<2,2>(WsPKV, bsPKV, wv, lane);
  float l3f[32];                                   // l3 weights cross S12
  load16p(a.l3_w + quad*32, l3f);
  load16p(a.l3_w + quad*32 + 16, l3f+16);
  float l3b = a.l3_b[0];
  BAR();   // S12

  // ---- l3 (own rows) + alpha + v_r/v_u ; kp/vp fused -> Bb ----
  if (ar<15){
    int R = 15*wv + ar;
    float x[16], y[16];
    load16f(&Ab[R*136 + quad*32], x);
    load16f(&Ab[R*136 + quad*32 + 16], y);
    float p = 0.f;
    #pragma unroll
    for (int i=0;i<16;i++) p = fmaf(x[i], l3f[i], p);
    #pragma unroll
    for (int i=0;i<16;i++) p = fmaf(y[i], l3f[16+i], p);
    p += __shfl_xor(p,16,64); p += __shfl_xor(p,32,64);
    if (quad==0) lga[R] = p + l3b;
  }
  gemmF<2,4,2>(actTk, wfPKV, wv, lane,
    [&](int w,int wb,int mt,int r,v4f c){ v4bf o;
      #pragma unroll
      for (int k=0;k<4;k++) o[k]=(__bf16)c[k];
      *(v4bf*)&Bb[(mt*16+r)*136 + (w?64:0) + wb] = o; });
  if (lane<3){
    int T=3*wv+lane;
    float ml[5], mx=-1e9f;
    #pragma unroll
    for (int i=0;i<5;i++){ ml[i]=((float)mfb[T*5+i]>0.5f)? lga[T*5+i] : -1e9f; mx=fmaxf(mx,ml[i]); }
    float den=0.f, e[5];
    #pragma unroll
    for (int i=0;i<5;i++){ e[i]=__expf(ml[i]-mx)*(float)mfb[T*5+i]; den+=e[i]; }
    float inv=1.0f/(den+1e-9f);
    #pragma unroll
    for (int i=0;i<5;i++) lga[T*5+i]=e[i]*inv;
  }
  if (lane<18){
    int tg=lane/6, c=lane-tg*6;
    int T=3*wv+tg;
    float v=0.f;
    #pragma unroll
    for (int i=0;i<5;i++) v += lga[T*5+i]*(float)Ru[T*30+i*6+c];
    long tk = blkT0 + T;
    if (tk<ntok) a.out[tk*134+128+c]=v;
  }
  // pool query crosses S13; head index matches this lane's pool task
  int hp = (lane - (lane/20)*20)/5;                // (lane%20)/5, 0..3
  float qvh[16];
  load16p((const float*)(ws + W_QP) + hp*16, qvh);
  BAR();   // S13

  // ---- pooling attn (wave-parallel: 60 lanes, one (T,h,j) dot each) ----
  if (lane<60){
    int tg=lane/20, rem=lane-tg*20, h=rem/5, j=rem-h*5;
    int T=3*wv+tg;
    float kk[16]; load16f(&Bb[(T*5+j)*136 + h*16], kk);
    float d=0.f;
    #pragma unroll
    for (int dd=0;dd<16;dd++) d += qvh[dd]*kk[dd];
    pattn[T*32+h*8+j] = ((float)msfb[T*5+j]>0.5f)? d*0.25f : NEG_INF_F;
  }
  WAVE_LDS_FENCE();   // writers/readers in same wave
  if (lane<12){
    int tg=lane>>2, h=lane&3;
    int T=3*wv+tg;
    float* pp2 = pattn + T*32 + h*8;
    float lgv[5];
    #pragma unroll
    for (int j=0;j<5;j++) lgv[j]=pp2[j];
    float mx=NEG_INF_F;
    #pragma unroll
    for (int j=0;j<5;j++) mx = fmaxf(mx,lgv[j]);
    float sum=0.f, ex[5];
    #pragma unroll
    for (int j=0;j<5;j++){ ex[j]=__expf(lgv[j]-mx); sum+=ex[j]; }
    float inv=1.0f/sum;
    #pragma unroll
    for (int j=0;j<5;j++) pp2[j]=ex[j]*inv;
  }
  WAVE_LDS_FENCE();
  for (int it=lane; it<192; it+=64){
    int tg=it>>6, c=it&63, h=c>>4;
    int T=3*wv+tg;
    const float* pp2 = pattn + T*32 + h*8;
    float4 p4 = *(const float4*)pp2;
    float p4v = pp2[4];
    float o=0.f;
    o += p4.x*(float)Bb[(T*5+0)*136+64+c];
    o += p4.y*(float)Bb[(T*5+1)*136+64+c];
    o += p4.z*(float)Bb[(T*5+2)*136+64+c];
    o += p4.w*(float)Bb[(T*5+3)*136+64+c];
    o += p4v *(float)Bb[(T*5+4)*136+64+c];
    Po[T*64+c]=(__bf16)o;
  }
  auto wfPO = wload<2,1>(ws+W_PO, a.p_ob, wv, lane);
  BAR();   // S14

  // ---- p_ow -> Cc (x many) ----
  gemmW<2,1,1>([&](int,int kt,int r,int q){ return *(const v8bf*)(Po + (size_t)r*64 + q*8 + kt*32); },
    wfPO, wv, lane,
    [&](int wb,int mt,int r,v4f c){
      float mm = many[r];
      v4bf o;
      #pragma unroll
      for (int k=0;k<4;k++) o[k]=(__bf16)(c[k]*mm);
      *(v4bf*)&Cc[r*64+wb]=o; });
  auto wfH1 = wload<5,2>(ws+W_H1, a.h1_b, wv, lane);
  BAR();   // S15

  // ---- h1 (act = [Eg | Cc | Pe], K=160) -> Bb rows 0..15 ----
  gemmW<5,1,2>([&](int,int kt,int r,int q){
      if (kt==0) return *(const v8bf*)(Eg + (size_t)r*40 + q*8);
      if (kt<3)  return *(const v8bf*)(Cc + (size_t)r*64 + q*8 + (kt-1)*32);
      return *(const v8bf*)(Pe + (size_t)r*64 + q*8 + (kt-3)*32); },
    wfH1, wv, lane,
    [&](int wb,int mt,int r,v4f c){ v4bf o;
      #pragma unroll
      for (int k=0;k<4;k++) o[k]=(__bf16)gelu_f(c[k]);
      *(v4bf*)&Bb[r*136+wb]=o; });
  auto wfH2 = wload<4,2>(ws+W_H2, a.h2_b, wv, lane);
  BAR();   // S16
  // ---- h2 -> Ab rows 0..15 ----
  gemmW<4,1,2>(actBb, wfH2, wv, lane,
    [&](int wb,int mt,int r,v4f c){ v4bf o;
      #pragma unroll
      for (int k=0;k<4;k++) o[k]=(__bf16)gelu_f(c[k]);
      *(v4bf*)&Ab[r*136+wb]=o; });
  auto wfH3 = wload<4,2>(ws+W_H3, a.h3_b, wv, lane);
  BAR();   // S17
  // ---- h3 -> out ----
  gemmW<4,1,2>(actAb, wfH3, wv, lane,
    [&](int wb,int mt,int r,v4f c){
      long tk = blkT0 + r;
      if (r<12 && tk<ntok){
        float2* o2 = (float2*)&a.out[tk*134 + wb];
        o2[0] = make_float2(c[0], c[1]);
        o2[1] = make_float2(c[2], c[3]);
      } });
}

extern "C" void kernel_launch(void* const* d_in, const int* in_sizes, int n_in,
                              void* d_out, int out_size, void* d_ws, size_t ws_size,
                              hipStream_t stream)
{
  P a;
  const float** pp = reinterpret_cast<const float**>(&a);
  for (int i=0;i<50;i++) pp[i] = reinterpret_cast<const float*>(d_in[i]);
  a.out = reinterpret_cast<float*>(d_out);
  int ntok = in_sizes[0] / DOBS;   // 65536

  __bf16* ws = reinterpret_cast<__bf16*>(d_ws);
  hipLaunchKernelGGL(prep_w, dim3(173), dim3(256), 0, stream, a, ws);
  hipLaunchKernelGGL(swarm_mfma, dim3((ntok+11)/12), dim3(256), 0, stream, a, ws, ntok);
}